// Round 14
// baseline (759.853 us; speedup 1.0000x reference)
//
#include <hip/hip_runtime.h>
#include <hip/hip_bf16.h>

// DGCNN forward on MI355X. B=8, N=2048, K=20.
// Round 30: dist_mfma is top (50us x3; WRITE 131MB @3.7TB/s, 64 scalar
// stores/lane). Swap MFMA operand order (mfma(B,A)) so the C fragment is
// transposed: lane holds 4 CONSECUTIVE output columns -> 16 f32x4 stores
// per lane instead of 64 scalar (4x fewer store insts, 1KB/inst vs 256B).
// fp16x3 term set preserved (BhAh+BlAh+BhAl = same three products). Same
// transform in gemm_hl and gemm_mfma_bt (acc stored directly as f32x4).
// r29 carried: reversed knn row map + scan-compact + bitonic-64 fast path.
// r28: no NT on re-read buffers. r27: BW seq_part. r25: gemm_hl, fc1_par,
// mlp_tail, fp16x3 dist path.

#define NEG_INF (-3.402823466e38f)
#define POS_INF (3.402823466e38f)

typedef __attribute__((ext_vector_type(8))) short short8;
typedef __attribute__((ext_vector_type(8))) _Float16 half8;
typedef __attribute__((ext_vector_type(4))) float f32x4;

__device__ __forceinline__ float lk(float x) { return x > 0.f ? x : 0.2f * x; }

__device__ __forceinline__ bool pair_gt(float va, int ma, float vb, int mb) {
  return va > vb || (va == vb && ma < mb);
}

// ---------------- dtype probe: 1 = bf16, 0 = fp32 ----------------
__global__ void detect_dtype(const unsigned short* __restrict__ x16, int* __restrict__ flag) {
  if (threadIdx.x == 0 && blockIdx.x == 0) {
    int sane = 0;
    for (int i = 0; i < 64; ++i) {
      unsigned short u = x16[2 * i];
      int e = (u >> 7) & 0xff;
      if (e == 0 || (e >= 90 && e <= 140)) ++sane;
    }
    *flag = (sane >= 32) ? 1 : 0;
  }
}

// ---------------- batched convert-to-fp32 of all inputs ----------------
struct ConvTable {
  const void* src[30];
  float* dst[30];
  int n[30];
};

__global__ void conv_all(ConvTable t, const int* __restrict__ flag) {
  int e = blockIdx.y;
  int n = t.n[e];
  bool isbf = (*flag != 0);
  for (int i = blockIdx.x * 256 + threadIdx.x; i < n; i += gridDim.x * 256) {
    float v;
    if (isbf) v = __bfloat162float(((const __hip_bfloat16*)t.src[e])[i]);
    else      v = ((const float*)t.src[e])[i];
    t.dst[e][i] = v;
  }
}

__global__ void convf2b(const float* __restrict__ in, __hip_bfloat16* __restrict__ out, int n) {
  int i = blockIdx.x * 256 + threadIdx.x;
  if (i < n) out[i] = __float2bfloat16(in[i]);
}

// ---------------- squared norms: SINGLE fmaf chain ascending c --------------
template <int C>
__global__ void sq_kernel(const float* __restrict__ xin, int ldx, float* __restrict__ sqb, int total) {
  int i = blockIdx.x * 256 + threadIdx.x;
  if (i >= total) return;
  const float* p = xin + (size_t)i * ldx;
  float s = 0.f;
  if (C == 3) {
    s = fmaf(p[0], p[0], s); s = fmaf(p[1], p[1], s); s = fmaf(p[2], p[2], s);
  } else {
#pragma unroll
    for (int c = 0; c < C; c += 4) {
      float4 xv = *(const float4*)(p + c);
      s = fmaf(xv.x, xv.x, s);
      s = fmaf(xv.y, xv.y, s);
      s = fmaf(xv.z, xv.z, s);
      s = fmaf(xv.w, xv.w, s);
    }
  }
  sqb[i] = s;
}

// ---------------- distance GEMM (C==3, layer 1): exact fp32 ----------------
__global__ __launch_bounds__(256) void dist_gemm(
    const float* __restrict__ xin, int ldx, const float* __restrict__ sqb,
    float* __restrict__ dist, int N, int K) {
  __shared__ float As[16][68];
  __shared__ float Bs[16][68];
  const int tid = threadIdx.x;
  const int tx = tid & 15, ty = tid >> 4;
  const int mc0 = blockIdx.x * 64;
  const int qr0 = blockIdx.y * 64;
  const int b = blockIdx.z;
  float acc[4][4] = {};
  const int nkt = (K + 15) / 16;
  for (int kt = 0; kt < nkt; ++kt) {
    int k0 = kt * 16;
#pragma unroll
    for (int ph = 0; ph < 4; ++ph) {
      int idx = tid + 256 * ph;
      int k = idx & 15, r = idx >> 4;
      float v = 0.f;
      if (k0 + k < K) v = xin[(size_t)(b * N + qr0 + r) * ldx + k0 + k];
      As[k][r] = v;
    }
#pragma unroll
    for (int ph = 0; ph < 4; ++ph) {
      int idx = tid + 256 * ph;
      int k = idx & 15, r = idx >> 4;
      float v = 0.f;
      if (k0 + k < K) v = xin[(size_t)(b * N + mc0 + r) * ldx + k0 + k];
      Bs[k][r] = v;
    }
    __syncthreads();
#pragma unroll
    for (int kk = 0; kk < 16; ++kk) {
      float av[4], bv[4];
#pragma unroll
      for (int r = 0; r < 4; ++r) av[r] = As[kk][4 * ty + r];
#pragma unroll
      for (int c = 0; c < 4; ++c) bv[c] = Bs[kk][4 * tx + c];
#pragma unroll
      for (int r = 0; r < 4; ++r)
#pragma unroll
        for (int c = 0; c < 4; ++c) acc[r][c] = fmaf(av[r], bv[c], acc[r][c]);
    }
    __syncthreads();
  }
  float sqq[4], sqm[4];
#pragma unroll
  for (int r = 0; r < 4; ++r) sqq[r] = sqb[b * N + qr0 + 4 * ty + r];
#pragma unroll
  for (int c = 0; c < 4; ++c) sqm[c] = sqb[b * N + mc0 + 4 * tx + c];
#pragma unroll
  for (int r = 0; r < 4; ++r) {
    f32x4 o;
#pragma unroll
    for (int c = 0; c < 4; ++c) {
      float t = sqq[r] - 2.f * acc[r][c];
      t = t + sqm[c];
      o[c] = -t;
    }
    // plain store: DIST is re-read by knn_select -- keep it L3-resident
    *(f32x4*)&dist[((size_t)(b * N + qr0 + 4 * ty + r)) * 2048 + mc0 + 4 * tx] = o;
  }
}

// ---------------- distance GEMM (layers 2-4): fp16x3 MFMA, transposed -------
// acc = mfma(B,A): lane holds 4 consecutive OUTPUT COLUMNS -> f32x4 stores.
// inner = Bh.Ah + Bl.Ah + Bh.Al == hi.hi + hi.lo + lo.hi (fp32 accum).
// Hi/lo planes have row stride 256 (HCAT cols 0-255 only).
// Diagonal forced to +1.0f: self is always the rank-0 pick in knn_select,
// which is then dropped (matches reference's idx[:,:,1:]).
__global__ __launch_bounds__(256) void dist_mfma(
    const _Float16* __restrict__ Xh, const _Float16* __restrict__ Xl,
    const float* __restrict__ sqb, float* __restrict__ dist, int N, int K) {
  __shared__ __align__(16) _Float16 Ah[128][40];
  __shared__ __align__(16) _Float16 Al[128][40];
  __shared__ __align__(16) _Float16 Bh[128][40];
  __shared__ __align__(16) _Float16 Bl[128][40];
  const int tid = threadIdx.x;
  const int lane = tid & 63;
  const int wave = tid >> 6;
  const int wm = (wave >> 1) * 64;
  const int wn = (wave & 1) * 64;
  const int mc0 = blockIdx.x * 128;   // neighbor cols
  const int qr0 = blockIdx.y * 128;   // query rows
  const size_t rb = (size_t)blockIdx.z * N;
  const int srow = tid >> 1, skq = (tid & 1) * 16;
  const int fr = lane & 15, fq = (lane >> 4) * 8;
  f32x4 acc[4][4] = {};
#pragma unroll 1
  for (int k0 = 0; k0 < K; k0 += 32) {
    const _Float16* pah = &Xh[(rb + qr0 + srow) * 256 + k0 + skq];
    const _Float16* pal = &Xl[(rb + qr0 + srow) * 256 + k0 + skq];
    const _Float16* pbh = &Xh[(rb + mc0 + srow) * 256 + k0 + skq];
    const _Float16* pbl = &Xl[(rb + mc0 + srow) * 256 + k0 + skq];
    half8 ah0 = *(const half8*)pah;  half8 ah1 = *(const half8*)(pah + 8);
    half8 al0 = *(const half8*)pal;  half8 al1 = *(const half8*)(pal + 8);
    half8 bh0 = *(const half8*)pbh;  half8 bh1 = *(const half8*)(pbh + 8);
    half8 bl0 = *(const half8*)pbl;  half8 bl1 = *(const half8*)(pbl + 8);
    *(half8*)&Ah[srow][skq] = ah0;  *(half8*)&Ah[srow][skq + 8] = ah1;
    *(half8*)&Al[srow][skq] = al0;  *(half8*)&Al[srow][skq + 8] = al1;
    *(half8*)&Bh[srow][skq] = bh0;  *(half8*)&Bh[srow][skq + 8] = bh1;
    *(half8*)&Bl[srow][skq] = bl0;  *(half8*)&Bl[srow][skq + 8] = bl1;
    __syncthreads();
    half8 fah[4], fal[4], fbh[4], fbl[4];
#pragma unroll
    for (int s = 0; s < 4; ++s) {
      fah[s] = *(const half8*)&Ah[wm + s * 16 + fr][fq];
      fal[s] = *(const half8*)&Al[wm + s * 16 + fr][fq];
    }
#pragma unroll
    for (int t = 0; t < 4; ++t) {
      fbh[t] = *(const half8*)&Bh[wn + t * 16 + fr][fq];
      fbl[t] = *(const half8*)&Bl[wn + t * 16 + fr][fq];
    }
#pragma unroll
    for (int s = 0; s < 4; ++s)
#pragma unroll
      for (int t = 0; t < 4; ++t) {
        acc[s][t] = __builtin_amdgcn_mfma_f32_16x16x32_f16(fbh[t], fah[s], acc[s][t], 0, 0, 0);
        acc[s][t] = __builtin_amdgcn_mfma_f32_16x16x32_f16(fbl[t], fah[s], acc[s][t], 0, 0, 0);
        acc[s][t] = __builtin_amdgcn_mfma_f32_16x16x32_f16(fbh[t], fal[s], acc[s][t], 0, 0, 0);
      }
    __syncthreads();
  }
  // transposed C layout: row = lane&15 (A index), 4 consecutive cols per lane
  const int rlane = lane & 15, cquad = (lane >> 4) * 4;
#pragma unroll
  for (int s = 0; s < 4; ++s) {
    const int rowi = qr0 + wm + s * 16 + rlane;
    const float sqr = sqb[rb + rowi];
    const size_t rowoff = (rb + rowi) * 2048;
#pragma unroll
    for (int t = 0; t < 4; ++t) {
      const int colb = mc0 + wn + t * 16 + cquad;
      f32x4 sq4 = *(const f32x4*)&sqb[rb + colb];
      f32x4 o;
#pragma unroll
      for (int r = 0; r < 4; ++r) {
        float v = -(sqr - 2.f * acc[s][t][r] + sq4[r]);
        if (rowi == colb + r) v = 1.0f;
        o[r] = v;
      }
      *(f32x4*)&dist[rowoff + colb] = o;
    }
  }
}

// ---------------- UV GEMM (layers 2-4): fp16x3 MFMA, transposed C ----------
// acc = mfma(W,A): lane holds 4 consecutive output cols -> f32x4 stores.
__global__ __launch_bounds__(256) void gemm_hl(
    const _Float16* __restrict__ Ahp, const _Float16* __restrict__ Alp,
    const _Float16* __restrict__ Whp, const _Float16* __restrict__ Wlp,
    float* __restrict__ Cm, int ldc, int K) {
  __shared__ __align__(16) _Float16 Ah[128][40];
  __shared__ __align__(16) _Float16 Al[128][40];
  __shared__ __align__(16) _Float16 Bh[128][40];
  __shared__ __align__(16) _Float16 Bl[128][40];
  const int tid = threadIdx.x;
  const int lane = tid & 63;
  const int wave = tid >> 6;
  const int wm = (wave >> 1) * 64;
  const int wn = (wave & 1) * 64;
  const int n0 = blockIdx.x * 128;    // W rows (output cols)
  const int m0 = blockIdx.y * 128;    // A rows
  const int srow = tid >> 1, skq = (tid & 1) * 16;
  const int fr = lane & 15, fq = (lane >> 4) * 8;
  f32x4 acc[4][4] = {};
#pragma unroll 1
  for (int k0 = 0; k0 < K; k0 += 32) {
    const _Float16* pah = &Ahp[(size_t)(m0 + srow) * 256 + k0 + skq];
    const _Float16* pal = &Alp[(size_t)(m0 + srow) * 256 + k0 + skq];
    const _Float16* pbh = &Whp[(size_t)(n0 + srow) * K + k0 + skq];
    const _Float16* pbl = &Wlp[(size_t)(n0 + srow) * K + k0 + skq];
    half8 ah0 = *(const half8*)pah;  half8 ah1 = *(const half8*)(pah + 8);
    half8 al0 = *(const half8*)pal;  half8 al1 = *(const half8*)(pal + 8);
    half8 bh0 = *(const half8*)pbh;  half8 bh1 = *(const half8*)(pbh + 8);
    half8 bl0 = *(const half8*)pbl;  half8 bl1 = *(const half8*)(pbl + 8);
    *(half8*)&Ah[srow][skq] = ah0;  *(half8*)&Ah[srow][skq + 8] = ah1;
    *(half8*)&Al[srow][skq] = al0;  *(half8*)&Al[srow][skq + 8] = al1;
    *(half8*)&Bh[srow][skq] = bh0;  *(half8*)&Bh[srow][skq + 8] = bh1;
    *(half8*)&Bl[srow][skq] = bl0;  *(half8*)&Bl[srow][skq + 8] = bl1;
    __syncthreads();
    half8 fah[4], fal[4], fbh[4], fbl[4];
#pragma unroll
    for (int s = 0; s < 4; ++s) {
      fah[s] = *(const half8*)&Ah[wm + s * 16 + fr][fq];
      fal[s] = *(const half8*)&Al[wm + s * 16 + fr][fq];
    }
#pragma unroll
    for (int t = 0; t < 4; ++t) {
      fbh[t] = *(const half8*)&Bh[wn + t * 16 + fr][fq];
      fbl[t] = *(const half8*)&Bl[wn + t * 16 + fr][fq];
    }
#pragma unroll
    for (int s = 0; s < 4; ++s)
#pragma unroll
      for (int t = 0; t < 4; ++t) {
        acc[s][t] = __builtin_amdgcn_mfma_f32_16x16x32_f16(fbh[t], fah[s], acc[s][t], 0, 0, 0);
        acc[s][t] = __builtin_amdgcn_mfma_f32_16x16x32_f16(fbl[t], fah[s], acc[s][t], 0, 0, 0);
        acc[s][t] = __builtin_amdgcn_mfma_f32_16x16x32_f16(fbh[t], fal[s], acc[s][t], 0, 0, 0);
      }
    __syncthreads();
  }
  const int rlane = lane & 15, cquad = (lane >> 4) * 4;
#pragma unroll
  for (int s = 0; s < 4; ++s) {
    const int row = m0 + wm + s * 16 + rlane;
    const size_t rowoff = (size_t)row * ldc;
#pragma unroll
    for (int t = 0; t < 4; ++t) {
      const int colb = n0 + wn + t * 16 + cquad;
      *(f32x4*)&Cm[rowoff + colb] = acc[s][t];
    }
  }
}

// ---------------- knn selection: threshold screen + bitonic sort ------------
// One wave per query row, block->row map REVERSED (read newest-written DIST
// first: LRU-friendly). Total order: (value desc, index asc) -- identical tie
// semantics to jax.lax.top_k. Rank 0 (self / diag) is dropped.
__global__ __launch_bounds__(256) void knn_select(
    const float* __restrict__ dist, int* __restrict__ idxout, int K) {
  __shared__ float cvs[4][128];
  __shared__ int   cis[4][128];
  const int lane = threadIdx.x & 63;
  const int wave = threadIdx.x >> 6;
  const int row = (gridDim.x - 1 - blockIdx.x) * 4 + wave;   // b*N + q (reversed)
  const float* dr = dist + (size_t)row * 2048;

  // P1: load this lane's 32 elements into registers; track best pair
  float rv[32];
  float bv = NEG_INF; int bi = 0x7fffffff;
#pragma unroll
  for (int i = 0; i < 8; ++i) {
    float4 vv = *(const float4*)(dr + i * 256 + lane * 4);
#pragma unroll
    for (int c = 0; c < 4; ++c) {
      float v = (&vv.x)[c];
      rv[i * 4 + c] = v;
      int m = i * 256 + lane * 4 + c;
      if (pair_gt(v, m, bv, bi)) { bv = v; bi = m; }
    }
  }

  // P2: bitonic sort the 64 lane-best pairs, descending
#pragma unroll
  for (int k = 2; k <= 64; k <<= 1) {
#pragma unroll
    for (int j = k >> 1; j >= 1; j >>= 1) {
      float pv = __shfl_xor(bv, j);
      int   pi = __shfl_xor(bi, j);
      bool lower = ((lane & j) == 0);
      bool desc  = ((lane & k) == 0);
      bool pG = pair_gt(pv, pi, bv, bi);
      bool take = (lower == desc) ? pG : !pG;
      bv = take ? pv : bv;
      bi = take ? pi : bi;
    }
  }
  // T0 = 21st largest lane-best. The 21 distinct lane-bests at ranks 0..20
  // are all >= T0, so any element < T0 has >= 21 elements above it =>
  // true top-21 of the row is a subset of {pairs >= T0}.
  const float T0v = __shfl(bv, 20);
  const int   T0i = __shfl(bi, 20);

  // P3: lane-local count + prefix scan + self-indexed compaction (E[M] ~ 25).
  int cntl = 0;
#pragma unroll
  for (int e = 0; e < 32; ++e) {
    float v = rv[e];
    int m = (e >> 2) * 256 + lane * 4 + (e & 3);
    cntl += (!pair_gt(T0v, T0i, v, m)) ? 1 : 0;
  }
  int pre = cntl;
#pragma unroll
  for (int s = 1; s < 64; s <<= 1) {
    int up = __shfl_up(pre, s);
    if (lane >= s) pre += up;
  }
  const int M0 = __shfl(pre, 63);      // total candidates
  int wp = pre - cntl;                 // exclusive prefix = this lane's base
#pragma unroll
  for (int e = 0; e < 32; ++e) {
    float v = rv[e];
    int m = (e >> 2) * 256 + lane * 4 + (e & 3);
    if (!pair_gt(T0v, T0i, v, m)) {
      if (wp < 128) { cvs[wave][wp] = v; cis[wave][wp] = m; }
      ++wp;
    }
  }
  __syncthreads();
  const int M = M0 < 128 ? M0 : 128;

  if (M <= 64) {
    // P4 fast path (common case): single bitonic-64, descending
    float v0 = (lane < M) ? cvs[wave][lane] : NEG_INF;
    int   i0 = (lane < M) ? cis[wave][lane] : 0x7fffffff;
#pragma unroll
    for (int k = 2; k <= 64; k <<= 1) {
#pragma unroll
      for (int j = k >> 1; j >= 1; j >>= 1) {
        float pv = __shfl_xor(v0, j); int pi = __shfl_xor(i0, j);
        bool lower = ((lane & j) == 0);
        bool desc  = ((lane & k) == 0);
        bool pG = pair_gt(pv, pi, v0, i0);
        bool take = (lower == desc) ? pG : !pG;
        v0 = take ? pv : v0; i0 = take ? pi : i0;
      }
    }
    if (lane >= 1 && lane <= K)
      idxout[(size_t)row * K + (lane - 1)] = i0;
  } else {
    // P4 slow path: bitonic-128 over slots (slot = lane + 64*reg), descending
    float v0 = (lane < M)      ? cvs[wave][lane]      : NEG_INF;
    int   i0 = (lane < M)      ? cis[wave][lane]      : 0x7fffffff;
    float v1 = (lane + 64 < M) ? cvs[wave][lane + 64] : NEG_INF;
    int   i1 = (lane + 64 < M) ? cis[wave][lane + 64] : 0x7fffffff;
#pragma unroll
    for (int k = 2; k <= 128; k <<= 1) {
#pragma unroll
      for (int j = k >> 1; j >= 1; j >>= 1) {
        if (j == 64) {
          bool pG = pair_gt(v1, i1, v0, i0);
          float tv = pG ? v1 : v0; int ti = pG ? i1 : i0;
          v1 = pG ? v0 : v1; i1 = pG ? i0 : i1;
          v0 = tv; i0 = ti;
        } else {
          {
            float pv = __shfl_xor(v0, j); int pi = __shfl_xor(i0, j);
            bool lower = ((lane & j) == 0);
            bool desc  = ((lane & k) == 0);
            bool pG = pair_gt(pv, pi, v0, i0);
            bool take = (lower == desc) ? pG : !pG;
            v0 = take ? pv : v0; i0 = take ? pi : i0;
          }
          {
            const int s1 = lane + 64;
            float pv = __shfl_xor(v1, j); int pi = __shfl_xor(i1, j);
            bool lower = ((s1 & j) == 0);
            bool desc  = ((s1 & k) == 0);
            bool pG = pair_gt(pv, pi, v1, i1);
            bool take = (lower == desc) ? pG : !pG;
            v1 = take ? pv : v1; i1 = take ? pi : i1;
          }
        }
      }
    }
    if (lane >= 1 && lane <= K)
      idxout[(size_t)row * K + (lane - 1)] = i0;
  }
}

// ---------------- build [W2 ; W1-W2] from edge weight (O, 2C) ---------------
// fp32 + fp16 hi/lo planes (for the MFMA UV GEMM).
__global__ void wcomb_build(const float* __restrict__ w, float* __restrict__ wc,
                            _Float16* __restrict__ wch, _Float16* __restrict__ wcl,
                            int O, int C) {
  int i = blockIdx.x * 256 + threadIdx.x;
  if (i >= O * C) return;
  int o = i / C, c = i % C;
  float w1 = w[o * 2 * C + c];
  float w2 = w[o * 2 * C + C + c];
  float u = w2;            // u rows
  float v = w1 - w2;       // v rows
  wc[(size_t)o * C + c] = u;
  wc[(size_t)(O + o) * C + c] = v;
  _Float16 uh = (_Float16)u;
  _Float16 vh = (_Float16)v;
  wch[(size_t)o * C + c] = uh;
  wch[(size_t)(O + o) * C + c] = vh;
  wcl[(size_t)o * C + c] = (_Float16)(u - (float)uh);
  wcl[(size_t)(O + o) * C + c] = (_Float16)(v - (float)vh);
}

// ---------------- fp32 C = A(MxK,lda) * B(NcxK)^T (layer-1 UV gemm) ---------
__global__ __launch_bounds__(256) void gemm_abt(
    const float* __restrict__ A, int lda, const float* __restrict__ Bm,
    float* __restrict__ Cm, int ldc, int M, int Nc, int K) {
  __shared__ float As[16][68];
  __shared__ float Bs[16][68];
  const int tid = threadIdx.x;
  const int tx = tid & 15, ty = tid >> 4;
  const int n0 = blockIdx.x * 64;
  const int m0 = blockIdx.y * 64;
  float acc[4][4] = {};
  const int nkt = (K + 15) / 16;
  for (int kt = 0; kt < nkt; ++kt) {
    int k0 = kt * 16;
#pragma unroll
    for (int ph = 0; ph < 4; ++ph) {
      int idx = tid + 256 * ph;
      int k = idx & 15, mr = idx >> 4;
      float v = 0.f;
      if (k0 + k < K) v = A[(size_t)(m0 + mr) * lda + k0 + k];
      As[k][mr] = v;
    }
#pragma unroll
    for (int ph = 0; ph < 4; ++ph) {
      int idx = tid + 256 * ph;
      int k = idx & 15, nr = idx >> 4;
      float v = 0.f;
      if (k0 + k < K) v = Bm[(size_t)(n0 + nr) * K + k0 + k];
      Bs[k][nr] = v;
    }
    __syncthreads();
#pragma unroll
    for (int kk = 0; kk < 16; ++kk) {
      float av[4], bv[4];
#pragma unroll
      for (int r = 0; r < 4; ++r) av[r] = As[kk][4 * ty + r];
#pragma unroll
      for (int c = 0; c < 4; ++c) bv[c] = Bs[kk][4 * tx + c];
#pragma unroll
      for (int r = 0; r < 4; ++r)
#pragma unroll
        for (int c = 0; c < 4; ++c) acc[r][c] = fmaf(av[r], bv[c], acc[r][c]);
    }
    __syncthreads();
  }
#pragma unroll
  for (int r = 0; r < 4; ++r) {
    float4 v = make_float4(acc[r][0], acc[r][1], acc[r][2], acc[r][3]);
    *(float4*)&Cm[(size_t)(m0 + 4 * ty + r) * ldc + n0 + 4 * tx] = v;
  }
}

// ---------------- MFMA bf16 GEMM: C = A(MxK) * B(NcxK)^T, transposed C ------
__global__ __launch_bounds__(256) void gemm_mfma_bt(
    const __hip_bfloat16* __restrict__ A, const __hip_bfloat16* __restrict__ Bm,
    float* __restrict__ Cm, int ldc, int M, int Nc, int K) {
  __shared__ __align__(16) __hip_bfloat16 Asm[128][40];
  __shared__ __align__(16) __hip_bfloat16 Bsm[128][40];
  const int tid = threadIdx.x;
  const int lane = tid & 63;
  const int wave = tid >> 6;
  const int wm = (wave >> 1) * 64;
  const int wn = (wave & 1) * 64;
  const int m0 = blockIdx.y * 128;
  const int n0 = blockIdx.x * 128;
  const int srow = tid >> 1, skq = (tid & 1) * 16;
  f32x4 acc[4][4] = {};
#pragma unroll 1
  for (int k0 = 0; k0 < K; k0 += 32) {
    short8 a0 = *(const short8*)&A[(size_t)(m0 + srow) * K + k0 + skq];
    short8 a1 = *(const short8*)&A[(size_t)(m0 + srow) * K + k0 + skq + 8];
    short8 b0 = *(const short8*)&Bm[(size_t)(n0 + srow) * K + k0 + skq];
    short8 b1 = *(const short8*)&Bm[(size_t)(n0 + srow) * K + k0 + skq + 8];
    *(short8*)&Asm[srow][skq] = a0;
    *(short8*)&Asm[srow][skq + 8] = a1;
    *(short8*)&Bsm[srow][skq] = b0;
    *(short8*)&Bsm[srow][skq + 8] = b1;
    __syncthreads();
    short8 af[4], bf_[4];
    const int fr = lane & 15, fq = (lane >> 4) * 8;
#pragma unroll
    for (int s = 0; s < 4; ++s)
      af[s] = *(const short8*)&Asm[wm + s * 16 + fr][fq];
#pragma unroll
    for (int t = 0; t < 4; ++t)
      bf_[t] = *(const short8*)&Bsm[wn + t * 16 + fr][fq];
#pragma unroll
    for (int s = 0; s < 4; ++s)
#pragma unroll
      for (int t = 0; t < 4; ++t)
        acc[s][t] = __builtin_amdgcn_mfma_f32_16x16x32_bf16(bf_[t], af[s], acc[s][t], 0, 0, 0);
    __syncthreads();
  }
  const int rlane = lane & 15, cquad = (lane >> 4) * 4;
#pragma unroll
  for (int s = 0; s < 4; ++s) {
    const int row = m0 + wm + s * 16 + rlane;
    const size_t rowoff = (size_t)row * ldc;
#pragma unroll
    for (int t = 0; t < 4; ++t) {
      const int colb = n0 + wn + t * 16 + cquad;
      // plain store: H1024 is re-read by seq_part -- keep it L3-resident
      *(f32x4*)&Cm[rowoff + colb] = acc[s][t];
    }
  }
}

// ---------------- edge conv pass1: h = v_n + u_m; stats + max/min over k ----
// K=20 hardcoded; all 20 indices prefetched then 20 independent gathers.
__global__ void edge_pass1(const float* __restrict__ uv, const int* __restrict__ idx,
                           float* __restrict__ hmax, float* __restrict__ hmin,
                           float* __restrict__ part, int N, int O) {
  int b = blockIdx.y, n = blockIdx.x, o = threadIdx.x;
  size_t row = (size_t)b * N + n;
  const int twoO = 2 * O;
  float vv = uv[row * twoO + O + o];
  const int* ib = idx + row * 20;
  int mi[20];
#pragma unroll
  for (int k = 0; k < 20; ++k) mi[k] = ib[k];
  float hv[20];
#pragma unroll
  for (int k = 0; k < 20; ++k)
    hv[k] = vv + uv[((size_t)b * N + mi[k]) * twoO + o];
  float mx = NEG_INF, mn = POS_INF, s = 0.f, ss = 0.f;
#pragma unroll
  for (int k = 0; k < 20; ++k) {
    mx = fmaxf(mx, hv[k]); mn = fminf(mn, hv[k]);
    s += hv[k]; ss = fmaf(hv[k], hv[k], ss);
  }
  hmax[row * O + o] = mx;
  hmin[row * O + o] = mn;
  __shared__ float2 red[256];
  red[o] = make_float2(s, ss);
  __syncthreads();
  int gsz = O >> 2;
  int lane = o & (gsz - 1);
  for (int off = gsz >> 1; off > 0; off >>= 1) {
    if (lane < off) { red[o].x += red[o + off].x; red[o].y += red[o + off].y; }
    __syncthreads();
  }
  if (lane == 0) {
    int g = o / gsz;
    part[row * 8 + g * 2] = red[o].x;
    part[row * 8 + g * 2 + 1] = red[o].y;
  }
}

__global__ void stats_reduce(const float* __restrict__ part, float* __restrict__ st, int N) {
  int g = blockIdx.x, b = blockIdx.y, tid = threadIdx.x;
  float s = 0.f, ss = 0.f;
  for (int n = tid; n < N; n += 256) {
    size_t base = ((size_t)b * N + n) * 8 + g * 2;
    s += part[base]; ss += part[base + 1];
  }
  __shared__ float2 red[256];
  red[tid] = make_float2(s, ss);
  __syncthreads();
  for (int off = 128; off > 0; off >>= 1) {
    if (tid < off) { red[tid].x += red[tid + off].x; red[tid].y += red[tid + off].y; }
    __syncthreads();
  }
  if (tid == 0) { st[(b * 4 + g) * 2] = red[0].x; st[(b * 4 + g) * 2 + 1] = red[0].y; }
}

__global__ void edge_pass2(const float* __restrict__ hmax, const float* __restrict__ hmin,
                           const float* __restrict__ st,
                           const float* __restrict__ gw, const float* __restrict__ gb,
                           float* __restrict__ outbase, __hip_bfloat16* __restrict__ outbf,
                           _Float16* __restrict__ outh, _Float16* __restrict__ outl,
                           int N, int O, int K, int coloff, int total) {
  int i = blockIdx.x * 256 + threadIdx.x;
  if (i >= total) return;
  int o = i % O;
  int n = (i / O) % N;
  int b = i / (O * N);
  int gsz = O >> 2;
  int g = o / gsz;
  float S = st[(b * 4 + g) * 2], SS = st[(b * 4 + g) * 2 + 1];
  float cnt = (float)N * (float)K * (float)gsz;
  float mean = S / cnt;
  float var = SS / cnt - mean * mean;
  float rs = rsqrtf(var + 1e-5f);
  float wf = gw[o], bf = gb[o];
  float Mv = (wf >= 0.f) ? hmax[i] : hmin[i];
  float val = lk((Mv - mean) * rs * wf + bf);
  size_t pos = ((size_t)b * N + n) * 512 + coloff + o;
  outbase[pos] = val;
  outbf[pos] = __float2bfloat16(val);
  if (outh) {
    // hi/lo fp16 planes, row stride 256 (cols 0-255 of HCAT only)
    size_t posh = ((size_t)b * N + n) * 256 + coloff + o;
    _Float16 h = (_Float16)val;
    outh[posh] = h;
    outl[posh] = (_Float16)(val - (float)h);
  }
}

// ---------------- gn_seq stats: grid (8,128); one f32x4-col x 16 rows -------
__global__ __launch_bounds__(256) void seq_part(const float* __restrict__ h,
                                                float4* __restrict__ pq, int N) {
  const int b = blockIdx.x, chunk = blockIdx.y;
  const int tid = threadIdx.x;        // cols 4*tid .. 4*tid+3
  const int nbeg = chunk * 16;
  float mx0 = NEG_INF, mx1 = NEG_INF, mx2 = NEG_INF, mx3 = NEG_INF;
  float mn0 = POS_INF, mn1 = POS_INF, mn2 = POS_INF, mn3 = POS_INF;
  float s0 = 0.f, s1 = 0.f, s2 = 0.f, s3 = 0.f;
  float q0 = 0.f, q1 = 0.f, q2 = 0.f, q3 = 0.f;
#pragma unroll
  for (int n = 0; n < 16; ++n) {
    f32x4 v = *(const f32x4*)&h[((size_t)b * N + nbeg + n) * 1024 + 4 * tid];
    mx0 = fmaxf(mx0, v[0]); mn0 = fminf(mn0, v[0]); s0 += v[0]; q0 = fmaf(v[0], v[0], q0);
    mx1 = fmaxf(mx1, v[1]); mn1 = fminf(mn1, v[1]); s1 += v[1]; q1 = fmaf(v[1], v[1], q1);
    mx2 = fmaxf(mx2, v[2]); mn2 = fminf(mn2, v[2]); s2 += v[2]; q2 = fmaf(v[2], v[2], q2);
    mx3 = fmaxf(mx3, v[3]); mn3 = fminf(mn3, v[3]); s3 += v[3]; q3 = fmaf(v[3], v[3], q3);
  }
  const size_t base = ((size_t)(b * 128 + chunk)) * 1024 + 4 * tid;
  pq[base + 0] = make_float4(mx0, mn0, s0, q0);
  pq[base + 1] = make_float4(mx1, mn1, s1, q1);
  pq[base + 2] = make_float4(mx2, mn2, s2, q2);
  pq[base + 3] = make_float4(mx3, mn3, s3, q3);
}

__global__ void seq_fin(const float4* __restrict__ pq, float* __restrict__ st16,
                        float* __restrict__ maxv, float* __restrict__ minv) {
  int b = blockIdx.y;
  int tid = threadIdx.x;
  int c = blockIdx.x * 256 + tid;
  float mx = NEG_INF, mn = POS_INF, s = 0.f, ss = 0.f;
#pragma unroll 8
  for (int ch = 0; ch < 128; ++ch) {
    float4 p = pq[((size_t)(b * 128 + ch)) * 1024 + c];
    mx = fmaxf(mx, p.x); mn = fminf(mn, p.y);
    s += p.z; ss += p.w;
  }
  maxv[b * 1024 + c] = mx;
  minv[b * 1024 + c] = mn;
  __shared__ float2 red[256];
  red[tid] = make_float2(s, ss);
  __syncthreads();
  int lane = tid & 63;
  for (int off = 32; off > 0; off >>= 1) {
    if (lane < off) { red[tid].x += red[tid + off].x; red[tid].y += red[tid + off].y; }
    __syncthreads();
  }
  if (lane == 0) {
    int g = c >> 6;
    st16[(b * 16 + g) * 2] = red[tid].x;
    st16[(b * 16 + g) * 2 + 1] = red[tid].y;
  }
}

__global__ void seq_apply(const float* __restrict__ st16, const float* __restrict__ maxv,
                          const float* __restrict__ minv, const float* __restrict__ gw,
                          const float* __restrict__ gb, float* __restrict__ g, int N) {
  int i = blockIdx.x * 256 + threadIdx.x;
  if (i >= 8 * 1024) return;
  int b = i >> 10, c = i & 1023;
  int grp = c >> 6;
  float S = st16[(b * 16 + grp) * 2], SS = st16[(b * 16 + grp) * 2 + 1];
  float cnt = (float)N * 64.f;
  float mean = S / cnt;
  float var = SS / cnt - mean * mean;
  float rs = rsqrtf(var + 1e-5f);
  float wf = gw[c], bf = gb[c];
  float Mv = (wf >= 0.f) ? maxv[i] : minv[i];
  g[i] = lk((Mv - mean) * rs * wf + bf);
}

// ---------------- MLP head, stage 1: fc1 (1024->512), one wave per output ---
__global__ __launch_bounds__(256) void fc1_par(
    const float* __restrict__ gvec, const float* __restrict__ w,
    const float* __restrict__ bias, float* __restrict__ z1) {
  __shared__ float xin[1024];
  const int b = blockIdx.y, tid = threadIdx.x;
  const int lane = tid & 63, wave = tid >> 6;
  for (int i = tid; i < 1024; i += 256) xin[i] = gvec[b * 1024 + i];
  __syncthreads();
  const int obase = blockIdx.x * 16 + wave * 4;
#pragma unroll
  for (int i = 0; i < 4; ++i) {
    const int o = obase + i;
    const float* wr = w + (size_t)o * 1024;
    float acc = 0.f;
#pragma unroll
    for (int r = 0; r < 4; ++r) {
      float4 wv = *(const float4*)(wr + r * 256 + lane * 4);
      float4 xv = *(const float4*)(&xin[r * 256 + lane * 4]);
      acc = fmaf(wv.x, xv.x, acc);
      acc = fmaf(wv.y, xv.y, acc);
      acc = fmaf(wv.z, xv.z, acc);
      acc = fmaf(wv.w, xv.w, acc);
    }
#pragma unroll
    for (int s = 1; s < 64; s <<= 1) acc += __shfl_xor(acc, s);
    if (lane == 0) z1[b * 512 + o] = acc + bias[o];
  }
}

// ---------------- MLP head, stage 2: ln1 -> fc2 -> ln2 -> fc3 -> ln3 -> fc4 -
__global__ __launch_bounds__(512) void mlp_tail(
    const float* __restrict__ z1in,
    const float* __restrict__ ln1w, const float* __restrict__ ln1b,
    const float* __restrict__ fc2w, const float* __restrict__ fc2b,
    const float* __restrict__ ln2w, const float* __restrict__ ln2b,
    const float* __restrict__ fc3w, const float* __restrict__ fc3b,
    const float* __restrict__ ln3w, const float* __restrict__ ln3b,
    const float* __restrict__ fc4w, const float* __restrict__ fc4b,
    void* __restrict__ out, const int* __restrict__ flag) {
  __shared__ float s1[512];
  __shared__ float z2[256];
  __shared__ float s2[256];
  __shared__ float z3[64];
  __shared__ float s3[64];
  __shared__ float2 red[8];
  const int b = blockIdx.x, tid = threadIdx.x;
  const int lane = tid & 63, wave = tid >> 6;

  // ---- ln1 over z1 (512) + leaky ----
  float v1 = z1in[b * 512 + tid];
  {
    float s = v1, ss = v1 * v1;
#pragma unroll
    for (int o = 1; o < 64; o <<= 1) { s += __shfl_xor(s, o); ss += __shfl_xor(ss, o); }
    if (lane == 0) red[wave] = make_float2(s, ss);
  }
  __syncthreads();
  {
    float S = 0.f, SS = 0.f;
#pragma unroll
    for (int i = 0; i < 8; ++i) { S += red[i].x; SS += red[i].y; }
    float mean = S / 512.f;
    float var = SS / 512.f - mean * mean;
    float rs = rsqrtf(var + 1e-5f);
    s1[tid] = lk((v1 - mean) * rs * ln1w[tid] + ln1b[tid]);
  }
  __syncthreads();

  // ---- fc2: 256 outputs x 512 in; 8 waves -> 32 outputs/wave ----
#pragma unroll 1
  for (int i = 0; i < 32; ++i) {
    const int o = wave * 32 + i;
    const float* wr = fc2w + (size_t)o * 512;
    float acc = 0.f;
#pragma unroll
    for (int r = 0; r < 2; ++r) {
      float4 wv = *(const float4*)(wr + r * 256 + lane * 4);
      float4 xv = *(const float4*)(&s1[r * 256 + lane * 4]);
      acc = fmaf(wv.x, xv.x, acc);
      acc = fmaf(wv.y, xv.y, acc);
      acc = fmaf(wv.z, xv.z, acc);
      acc = fmaf(wv.w, xv.w, acc);
    }
#pragma unroll
    for (int s = 1; s < 64; s <<= 1) acc += __shfl_xor(acc, s);
    if (lane == 0) z2[o] = acc + fc2b[o];
  }
  __syncthreads();

  // ---- ln2 over 256 + leaky ----
  float v2 = (tid < 256) ? z2[tid] : 0.f;
  {
    float s = v2, ss = v2 * v2;
#pragma unroll
    for (int o = 1; o < 64; o <<= 1) { s += __shfl_xor(s, o); ss += __shfl_xor(ss, o); }
    if (lane == 0) red[wave] = make_float2(s, ss);
  }
  __syncthreads();
  {
    float S = 0.f, SS = 0.f;
#pragma unroll
    for (int i = 0; i < 4; ++i) { S += red[i].x; SS += red[i].y; }
    float mean = S / 256.f;
    float var = SS / 256.f - mean * mean;
    float rs = rsqrtf(var + 1e-5f);
    if (tid < 256) s2[tid] = lk((v2 - mean) * rs * ln2w[tid] + ln2b[tid]);
  }
  __syncthreads();

  // ---- fc3: 64 outputs x 256 in; 8 waves -> 8 outputs/wave ----
#pragma unroll 1
  for (int i = 0; i < 8; ++i) {
    const int o = wave * 8 + i;
    const float* wr = fc3w + (size_t)o * 256;
    float4 wv = *(const float4*)(wr + lane * 4);
    float4 xv = *(const float4*)(&s2[lane * 4]);
    float acc = fmaf(wv.x, xv.x, 0.f);
    acc = fmaf(wv.y, xv.y, acc);
    acc = fmaf(wv.z, xv.z, acc);
    acc = fmaf(wv.w, xv.w, acc);
#pragma unroll
    for (int s = 1; s < 64; s <<= 1) acc += __shfl_xor(acc, s);
    if (lane == 0) z3[o] = acc + fc3b[o];
  }
  __syncthreads();

  // ---- ln3 over 64 + leaky (wave 0 only) ----
  if (wave == 0) {
    float v3 = z3[lane];
    float s = v3, ss = v3 * v3;
#pragma unroll
    for (int o = 1; o < 64; o <<= 1) { s += __shfl_xor(s, o); ss += __shfl_xor(ss, o); }
    float mean = s / 64.f;
    float var = ss / 64.f - mean * mean;
    float rs = rsqrtf(var + 1e-5f);
    s3[lane] = lk((v3 - mean) * rs * ln3w[lane] + ln3b[lane]);
  }
  __syncthreads();

  // ---- fc4: 2 outputs x 64 (waves 0,1) ----
  if (wave < 2) {
    float acc = s3[lane] * fc4w[wave * 64 + lane];
#pragma unroll
    for (int s = 1; s < 64; s <<= 1) acc += __shfl_xor(acc, s);
    if (lane == 0) {
      acc += fc4b[wave];
      if (*flag) ((__hip_bfloat16*)out)[b * 2 + wave] = __float2bfloat16(acc);
      else       ((float*)out)[b * 2 + wave] = acc;
    }
  }
}

// ---------------- host-side dispatch helpers -----------------------
static void launch_sq(int C, const float* xin, int ldx, float* sqb, int BN, hipStream_t s) {
  dim3 g((BN + 255) / 256);
  if (C == 3)       sq_kernel<3><<<g, 256, 0, s>>>(xin, ldx, sqb, BN);
  else if (C == 64) sq_kernel<64><<<g, 256, 0, s>>>(xin, ldx, sqb, BN);
  else              sq_kernel<128><<<g, 256, 0, s>>>(xin, ldx, sqb, BN);
}

extern "C" void kernel_launch(void* const* d_in, const int* in_sizes, int n_in,
                              void* d_out, int out_size, void* d_ws, size_t ws_size,
                              hipStream_t stream) {
  (void)out_size; (void)ws_size;
  const int B = 8, N = 2048, KNN = 20;
  const int BN = B * N;

  float* base = (float*)d_ws;
  size_t off = 0;
  auto alloc = [&](size_t nf) { float* p = base + off; off += nf; return p; };

  int*   FLAG  = (int*)alloc(16);
  float* XF    = alloc((size_t)BN * 3);
  float* HCAT  = alloc((size_t)BN * 512);
  float* DISTB = alloc((size_t)BN * 2048);   // DIST during knn; then UV|HMAX|HMIN|H1024
  float* UV    = DISTB;                       // BN*512
  float* HMAX  = DISTB + (size_t)BN * 512;    // BN*256
  float* HMIN  = DISTB + (size_t)BN * 768;    // BN*256
  float* H1024 = DISTB + (size_t)BN * 1024;   // BN*1024
  float* SQB   = alloc(BN);
  float* WCOMB = alloc((size_t)512 * 128);
  float* PART  = alloc((size_t)BN * 8);
  float* ST4   = alloc(64);
  float* ST16  = alloc(512);
  float* PQST  = alloc((size_t)8 * 128 * 1024 * 4);
  float* MAXV  = alloc(8 * 1024);
  float* MINV  = alloc(8 * 1024);
  float* GVEC  = alloc(8 * 1024);
  float* Z1    = alloc(8 * 512);
  int*   IDX = (int*)alloc((size_t)BN * KNN);
  __hip_bfloat16* HCATBF = (__hip_bfloat16*)alloc((size_t)BN * 256);  // BN*512 bf16
  __hip_bfloat16* WMBF   = (__hip_bfloat16*)alloc(262144);            // 1024*512 bf16
  _Float16* HH  = (_Float16*)alloc((size_t)BN * 128);  // BN*256 fp16 hi (stride 256)
  _Float16* HL  = (_Float16*)alloc((size_t)BN * 128);  // BN*256 fp16 lo (stride 256)
  _Float16* WCH = (_Float16*)alloc((size_t)512 * 64);  // 512*128 fp16 hi
  _Float16* WCL = (_Float16*)alloc((size_t)512 * 64);  // 512*128 fp16 lo

  // converted fp32 weights
  ConvTable ct;
  float* conv_dst[30];
  for (int i = 0; i < 30; ++i) {
    int n = in_sizes[i];
    conv_dst[i] = alloc((size_t)((n + 15) & ~15));
    ct.src[i] = d_in[i];
    ct.dst[i] = conv_dst[i];
    ct.n[i] = n;
  }
  ct.dst[0] = XF; ct.n[0] = BN * 3;

  const float* W_[4]  = {conv_dst[1], conv_dst[4], conv_dst[7], conv_dst[10]};
  const float* GW_[4] = {conv_dst[2], conv_dst[5], conv_dst[8], conv_dst[11]};
  const float* GB_[4] = {conv_dst[3], conv_dst[6], conv_dst[9], conv_dst[12]};
  const float* WM = conv_dst[13];
  const float* GMW = conv_dst[14], *GMB = conv_dst[15];
  const float* FC1W = conv_dst[16], *FC1B = conv_dst[17], *LN1W = conv_dst[18], *LN1B = conv_dst[19];
  const float* FC2W = conv_dst[20], *FC2B = conv_dst[21], *LN2W = conv_dst[22], *LN2B = conv_dst[23];
  const float* FC3W = conv_dst[24], *FC3B = conv_dst[25], *LN3W = conv_dst[26], *LN3B = conv_dst[27];
  const float* FC4W = conv_dst[28], *FC4B = conv_dst[29];

  detect_dtype<<<dim3(1), 64, 0, stream>>>((const unsigned short*)d_in[0], FLAG);
  conv_all<<<dim3(256, 30), 256, 0, stream>>>(ct, FLAG);
  convf2b<<<dim3(2048), 256, 0, stream>>>(WM, WMBF, 1024 * 512);

  const int Cs[4]     = {3, 64, 64, 128};
  const int Os[4]     = {64, 64, 128, 256};
  const int incol[4]  = {0, 0, 64, 128};
  const int outcol[4] = {0, 64, 128, 256};

  for (int l = 0; l < 4; ++l) {
    const int C = Cs[l], O = Os[l], twoO = 2 * O;
    const float* xin = (l == 0) ? XF : (HCAT + incol[l]);
    const int ldx = (l == 0) ? 3 : 512;

    launch_sq(C, xin, ldx, SQB, BN, stream);
    if (l == 0)
      dist_gemm<<<dim3(N / 64, N / 64, B), 256, 0, stream>>>(xin, ldx, SQB, DISTB, N, C);
    else
      dist_mfma<<<dim3(N / 128, N / 128, B), 256, 0, stream>>>(HH + incol[l], HL + incol[l],
                                                               SQB, DISTB, N, C);
    knn_select<<<dim3(BN / 4), 256, 0, stream>>>(DISTB, IDX, KNN);
    wcomb_build<<<dim3((O * C + 255) / 256), 256, 0, stream>>>(W_[l], WCOMB, WCH, WCL, O, C);
    if (l == 0)
      gemm_abt<<<dim3(twoO / 64, BN / 64), 256, 0, stream>>>(xin, ldx, WCOMB, UV, twoO, BN, twoO, C);
    else
      gemm_hl<<<dim3(twoO / 128, BN / 128), 256, 0, stream>>>(HH + incol[l], HL + incol[l],
                                                              WCH, WCL, UV, twoO, C);
    edge_pass1<<<dim3(N, B), O, 0, stream>>>(UV, IDX, HMAX, HMIN, PART, N, O);
    stats_reduce<<<dim3(4, B), 256, 0, stream>>>(PART, ST4, N);
    int tot = BN * O;
    // layer 4's output (cols 256-511) never feeds a distance GEMM: skip hi/lo
    _Float16* oh = (l == 3) ? nullptr : HH;
    _Float16* ol = (l == 3) ? nullptr : HL;
    edge_pass2<<<dim3((tot + 255) / 256), 256, 0, stream>>>(HMAX, HMIN, ST4, GW_[l], GB_[l],
                                                            HCAT, HCATBF, oh, ol,
                                                            N, O, KNN, outcol[l], tot);
  }

  gemm_mfma_bt<<<dim3(1024 / 128, BN / 128), 256, 0, stream>>>(HCATBF, WMBF, H1024, 1024, BN, 1024, 512);
  seq_part<<<dim3(8, 128), 256, 0, stream>>>(H1024, (float4*)PQST, N);
  seq_fin<<<dim3(4, 8), 256, 0, stream>>>((const float4*)PQST, ST16, MAXV, MINV);
  seq_apply<<<dim3(32), 256, 0, stream>>>(ST16, MAXV, MINV, GMW, GMB, GVEC, N);

  fc1_par<<<dim3(32, 8), 256, 0, stream>>>(GVEC, FC1W, FC1B, Z1);
  mlp_tail<<<dim3(8), 512, 0, stream>>>(Z1, LN1W, LN1B,
                                        FC2W, FC2B, LN2W, LN2B,
                                        FC3W, FC3B, LN3W, LN3B,
                                        FC4W, FC4B, d_out, FLAG);
}

// Round 15
// 732.016 us; speedup vs baseline: 1.0380x; 1.0380x over previous
//
#include <hip/hip_runtime.h>
#include <hip/hip_bf16.h>

// DGCNN forward on MI355X. B=8, N=2048, K=20.
// Round 31: REVERT r30 (transposed-C epilogue regressed dist_mfma 50->57.6us;
// store-issue theory falsified -- segment count unchanged, MFMA sched hurt).
// This is the r29 kernel verbatim (best measured: 732.3us).
// r29: reversed knn row map + scan-compact + bitonic-64 fast path.
// r28: no NT stores on re-read buffers (DIST/H1024 stay L3-resident).
// r27: BW-correct seq_part. r25: bitonic knn, gemm_hl UV GEMMs (fp16x3),
// fc1_par + mlp_tail. r18: fp16x3 MFMA distance GEMMs (diag forced +1.0).

#define NEG_INF (-3.402823466e38f)
#define POS_INF (3.402823466e38f)

typedef __attribute__((ext_vector_type(8))) short short8;
typedef __attribute__((ext_vector_type(8))) _Float16 half8;
typedef __attribute__((ext_vector_type(4))) float f32x4;

__device__ __forceinline__ float lk(float x) { return x > 0.f ? x : 0.2f * x; }

__device__ __forceinline__ bool pair_gt(float va, int ma, float vb, int mb) {
  return va > vb || (va == vb && ma < mb);
}

// ---------------- dtype probe: 1 = bf16, 0 = fp32 ----------------
__global__ void detect_dtype(const unsigned short* __restrict__ x16, int* __restrict__ flag) {
  if (threadIdx.x == 0 && blockIdx.x == 0) {
    int sane = 0;
    for (int i = 0; i < 64; ++i) {
      unsigned short u = x16[2 * i];
      int e = (u >> 7) & 0xff;
      if (e == 0 || (e >= 90 && e <= 140)) ++sane;
    }
    *flag = (sane >= 32) ? 1 : 0;
  }
}

// ---------------- batched convert-to-fp32 of all inputs ----------------
struct ConvTable {
  const void* src[30];
  float* dst[30];
  int n[30];
};

__global__ void conv_all(ConvTable t, const int* __restrict__ flag) {
  int e = blockIdx.y;
  int n = t.n[e];
  bool isbf = (*flag != 0);
  for (int i = blockIdx.x * 256 + threadIdx.x; i < n; i += gridDim.x * 256) {
    float v;
    if (isbf) v = __bfloat162float(((const __hip_bfloat16*)t.src[e])[i]);
    else      v = ((const float*)t.src[e])[i];
    t.dst[e][i] = v;
  }
}

__global__ void convf2b(const float* __restrict__ in, __hip_bfloat16* __restrict__ out, int n) {
  int i = blockIdx.x * 256 + threadIdx.x;
  if (i < n) out[i] = __float2bfloat16(in[i]);
}

// ---------------- squared norms: SINGLE fmaf chain ascending c --------------
template <int C>
__global__ void sq_kernel(const float* __restrict__ xin, int ldx, float* __restrict__ sqb, int total) {
  int i = blockIdx.x * 256 + threadIdx.x;
  if (i >= total) return;
  const float* p = xin + (size_t)i * ldx;
  float s = 0.f;
  if (C == 3) {
    s = fmaf(p[0], p[0], s); s = fmaf(p[1], p[1], s); s = fmaf(p[2], p[2], s);
  } else {
#pragma unroll
    for (int c = 0; c < C; c += 4) {
      float4 xv = *(const float4*)(p + c);
      s = fmaf(xv.x, xv.x, s);
      s = fmaf(xv.y, xv.y, s);
      s = fmaf(xv.z, xv.z, s);
      s = fmaf(xv.w, xv.w, s);
    }
  }
  sqb[i] = s;
}

// ---------------- distance GEMM (C==3, layer 1): exact fp32 ----------------
__global__ __launch_bounds__(256) void dist_gemm(
    const float* __restrict__ xin, int ldx, const float* __restrict__ sqb,
    float* __restrict__ dist, int N, int K) {
  __shared__ float As[16][68];
  __shared__ float Bs[16][68];
  const int tid = threadIdx.x;
  const int tx = tid & 15, ty = tid >> 4;
  const int mc0 = blockIdx.x * 64;
  const int qr0 = blockIdx.y * 64;
  const int b = blockIdx.z;
  float acc[4][4] = {};
  const int nkt = (K + 15) / 16;
  for (int kt = 0; kt < nkt; ++kt) {
    int k0 = kt * 16;
#pragma unroll
    for (int ph = 0; ph < 4; ++ph) {
      int idx = tid + 256 * ph;
      int k = idx & 15, r = idx >> 4;
      float v = 0.f;
      if (k0 + k < K) v = xin[(size_t)(b * N + qr0 + r) * ldx + k0 + k];
      As[k][r] = v;
    }
#pragma unroll
    for (int ph = 0; ph < 4; ++ph) {
      int idx = tid + 256 * ph;
      int k = idx & 15, r = idx >> 4;
      float v = 0.f;
      if (k0 + k < K) v = xin[(size_t)(b * N + mc0 + r) * ldx + k0 + k];
      Bs[k][r] = v;
    }
    __syncthreads();
#pragma unroll
    for (int kk = 0; kk < 16; ++kk) {
      float av[4], bv[4];
#pragma unroll
      for (int r = 0; r < 4; ++r) av[r] = As[kk][4 * ty + r];
#pragma unroll
      for (int c = 0; c < 4; ++c) bv[c] = Bs[kk][4 * tx + c];
#pragma unroll
      for (int r = 0; r < 4; ++r)
#pragma unroll
        for (int c = 0; c < 4; ++c) acc[r][c] = fmaf(av[r], bv[c], acc[r][c]);
    }
    __syncthreads();
  }
  float sqq[4], sqm[4];
#pragma unroll
  for (int r = 0; r < 4; ++r) sqq[r] = sqb[b * N + qr0 + 4 * ty + r];
#pragma unroll
  for (int c = 0; c < 4; ++c) sqm[c] = sqb[b * N + mc0 + 4 * tx + c];
#pragma unroll
  for (int r = 0; r < 4; ++r) {
    f32x4 o;
#pragma unroll
    for (int c = 0; c < 4; ++c) {
      float t = sqq[r] - 2.f * acc[r][c];
      t = t + sqm[c];
      o[c] = -t;
    }
    // plain store: DIST is re-read by knn_select -- keep it L3-resident
    *(f32x4*)&dist[((size_t)(b * N + qr0 + 4 * ty + r)) * 2048 + mc0 + 4 * tx] = o;
  }
}

// ---------------- distance GEMM (layers 2-4): fp16x3 MFMA -------------------
// inner = hi.hi + hi.lo + lo.hi (fp32 accum); error ~2^-22 rel per term.
// Hi/lo planes have row stride 256 (HCAT cols 0-255 only).
// Diagonal forced to +1.0f: self is always the rank-0 pick in knn_select,
// which is then dropped (matches reference's idx[:,:,1:]).
__global__ __launch_bounds__(256) void dist_mfma(
    const _Float16* __restrict__ Xh, const _Float16* __restrict__ Xl,
    const float* __restrict__ sqb, float* __restrict__ dist, int N, int K) {
  __shared__ __align__(16) _Float16 Ah[128][40];
  __shared__ __align__(16) _Float16 Al[128][40];
  __shared__ __align__(16) _Float16 Bh[128][40];
  __shared__ __align__(16) _Float16 Bl[128][40];
  const int tid = threadIdx.x;
  const int lane = tid & 63;
  const int wave = tid >> 6;
  const int wm = (wave >> 1) * 64;
  const int wn = (wave & 1) * 64;
  const int mc0 = blockIdx.x * 128;   // neighbor cols
  const int qr0 = blockIdx.y * 128;   // query rows
  const size_t rb = (size_t)blockIdx.z * N;
  const int srow = tid >> 1, skq = (tid & 1) * 16;
  const int fr = lane & 15, fq = (lane >> 4) * 8;
  f32x4 acc[4][4] = {};
#pragma unroll 1
  for (int k0 = 0; k0 < K; k0 += 32) {
    const _Float16* pah = &Xh[(rb + qr0 + srow) * 256 + k0 + skq];
    const _Float16* pal = &Xl[(rb + qr0 + srow) * 256 + k0 + skq];
    const _Float16* pbh = &Xh[(rb + mc0 + srow) * 256 + k0 + skq];
    const _Float16* pbl = &Xl[(rb + mc0 + srow) * 256 + k0 + skq];
    half8 ah0 = *(const half8*)pah;  half8 ah1 = *(const half8*)(pah + 8);
    half8 al0 = *(const half8*)pal;  half8 al1 = *(const half8*)(pal + 8);
    half8 bh0 = *(const half8*)pbh;  half8 bh1 = *(const half8*)(pbh + 8);
    half8 bl0 = *(const half8*)pbl;  half8 bl1 = *(const half8*)(pbl + 8);
    *(half8*)&Ah[srow][skq] = ah0;  *(half8*)&Ah[srow][skq + 8] = ah1;
    *(half8*)&Al[srow][skq] = al0;  *(half8*)&Al[srow][skq + 8] = al1;
    *(half8*)&Bh[srow][skq] = bh0;  *(half8*)&Bh[srow][skq + 8] = bh1;
    *(half8*)&Bl[srow][skq] = bl0;  *(half8*)&Bl[srow][skq + 8] = bl1;
    __syncthreads();
    half8 fah[4], fal[4], fbh[4], fbl[4];
#pragma unroll
    for (int s = 0; s < 4; ++s) {
      fah[s] = *(const half8*)&Ah[wm + s * 16 + fr][fq];
      fal[s] = *(const half8*)&Al[wm + s * 16 + fr][fq];
    }
#pragma unroll
    for (int t = 0; t < 4; ++t) {
      fbh[t] = *(const half8*)&Bh[wn + t * 16 + fr][fq];
      fbl[t] = *(const half8*)&Bl[wn + t * 16 + fr][fq];
    }
#pragma unroll
    for (int s = 0; s < 4; ++s)
#pragma unroll
      for (int t = 0; t < 4; ++t) {
        acc[s][t] = __builtin_amdgcn_mfma_f32_16x16x32_f16(fah[s], fbh[t], acc[s][t], 0, 0, 0);
        acc[s][t] = __builtin_amdgcn_mfma_f32_16x16x32_f16(fah[s], fbl[t], acc[s][t], 0, 0, 0);
        acc[s][t] = __builtin_amdgcn_mfma_f32_16x16x32_f16(fal[s], fbh[t], acc[s][t], 0, 0, 0);
      }
    __syncthreads();
  }
  const int ccol = lane & 15, crow = (lane >> 4) * 4;
  float sqm[4];
#pragma unroll
  for (int t = 0; t < 4; ++t) sqm[t] = sqb[rb + mc0 + wn + t * 16 + ccol];
#pragma unroll
  for (int s = 0; s < 4; ++s) {
#pragma unroll
    for (int r = 0; r < 4; ++r) {
      const int rowi = qr0 + wm + s * 16 + crow + r;
      const float sqr = sqb[rb + rowi];
      const size_t rowoff = (rb + rowi) * 2048;
#pragma unroll
      for (int t = 0; t < 4; ++t) {
        const int coli = mc0 + wn + t * 16 + ccol;
        float v = -(sqr - 2.f * acc[s][t][r] + sqm[t]);
        if (rowi == coli) v = 1.0f;
        // plain store: DIST is re-read by knn_select -- keep it L3-resident
        dist[rowoff + coli] = v;
      }
    }
  }
}

// ---------------- UV GEMM (layers 2-4): fp16x3 MFMA, C = A * W^T ------------
// A = hi/lo fp16 planes (row stride 256, pre-offset to incol); W = hi/lo
// fp16 planes of WCOMB (row stride K). fp32 accum, plain fp32 stores.
__global__ __launch_bounds__(256) void gemm_hl(
    const _Float16* __restrict__ Ahp, const _Float16* __restrict__ Alp,
    const _Float16* __restrict__ Whp, const _Float16* __restrict__ Wlp,
    float* __restrict__ Cm, int ldc, int K) {
  __shared__ __align__(16) _Float16 Ah[128][40];
  __shared__ __align__(16) _Float16 Al[128][40];
  __shared__ __align__(16) _Float16 Bh[128][40];
  __shared__ __align__(16) _Float16 Bl[128][40];
  const int tid = threadIdx.x;
  const int lane = tid & 63;
  const int wave = tid >> 6;
  const int wm = (wave >> 1) * 64;
  const int wn = (wave & 1) * 64;
  const int n0 = blockIdx.x * 128;    // W rows (output cols)
  const int m0 = blockIdx.y * 128;    // A rows
  const int srow = tid >> 1, skq = (tid & 1) * 16;
  const int fr = lane & 15, fq = (lane >> 4) * 8;
  f32x4 acc[4][4] = {};
#pragma unroll 1
  for (int k0 = 0; k0 < K; k0 += 32) {
    const _Float16* pah = &Ahp[(size_t)(m0 + srow) * 256 + k0 + skq];
    const _Float16* pal = &Alp[(size_t)(m0 + srow) * 256 + k0 + skq];
    const _Float16* pbh = &Whp[(size_t)(n0 + srow) * K + k0 + skq];
    const _Float16* pbl = &Wlp[(size_t)(n0 + srow) * K + k0 + skq];
    half8 ah0 = *(const half8*)pah;  half8 ah1 = *(const half8*)(pah + 8);
    half8 al0 = *(const half8*)pal;  half8 al1 = *(const half8*)(pal + 8);
    half8 bh0 = *(const half8*)pbh;  half8 bh1 = *(const half8*)(pbh + 8);
    half8 bl0 = *(const half8*)pbl;  half8 bl1 = *(const half8*)(pbl + 8);
    *(half8*)&Ah[srow][skq] = ah0;  *(half8*)&Ah[srow][skq + 8] = ah1;
    *(half8*)&Al[srow][skq] = al0;  *(half8*)&Al[srow][skq + 8] = al1;
    *(half8*)&Bh[srow][skq] = bh0;  *(half8*)&Bh[srow][skq + 8] = bh1;
    *(half8*)&Bl[srow][skq] = bl0;  *(half8*)&Bl[srow][skq + 8] = bl1;
    __syncthreads();
    half8 fah[4], fal[4], fbh[4], fbl[4];
#pragma unroll
    for (int s = 0; s < 4; ++s) {
      fah[s] = *(const half8*)&Ah[wm + s * 16 + fr][fq];
      fal[s] = *(const half8*)&Al[wm + s * 16 + fr][fq];
    }
#pragma unroll
    for (int t = 0; t < 4; ++t) {
      fbh[t] = *(const half8*)&Bh[wn + t * 16 + fr][fq];
      fbl[t] = *(const half8*)&Bl[wn + t * 16 + fr][fq];
    }
#pragma unroll
    for (int s = 0; s < 4; ++s)
#pragma unroll
      for (int t = 0; t < 4; ++t) {
        acc[s][t] = __builtin_amdgcn_mfma_f32_16x16x32_f16(fah[s], fbh[t], acc[s][t], 0, 0, 0);
        acc[s][t] = __builtin_amdgcn_mfma_f32_16x16x32_f16(fah[s], fbl[t], acc[s][t], 0, 0, 0);
        acc[s][t] = __builtin_amdgcn_mfma_f32_16x16x32_f16(fal[s], fbh[t], acc[s][t], 0, 0, 0);
      }
    __syncthreads();
  }
  const int ccol = lane & 15, crow = (lane >> 4) * 4;
#pragma unroll
  for (int s = 0; s < 4; ++s)
#pragma unroll
    for (int r = 0; r < 4; ++r) {
      const int row = m0 + wm + s * 16 + crow + r;
      const size_t rowoff = (size_t)row * ldc;
#pragma unroll
      for (int t = 0; t < 4; ++t) {
        const int col = n0 + wn + t * 16 + ccol;
        Cm[rowoff + col] = acc[s][t][r];
      }
    }
}

// ---------------- knn selection: threshold screen + bitonic sort ------------
// One wave per query row, block->row map REVERSED (read newest-written DIST
// first: LRU-friendly). Total order: (value desc, index asc) -- identical tie
// semantics to jax.lax.top_k. Rank 0 (self / diag) is dropped.
__global__ __launch_bounds__(256) void knn_select(
    const float* __restrict__ dist, int* __restrict__ idxout, int K) {
  __shared__ float cvs[4][128];
  __shared__ int   cis[4][128];
  const int lane = threadIdx.x & 63;
  const int wave = threadIdx.x >> 6;
  const int row = (gridDim.x - 1 - blockIdx.x) * 4 + wave;   // b*N + q (reversed)
  const float* dr = dist + (size_t)row * 2048;

  // P1: load this lane's 32 elements into registers; track best pair
  float rv[32];
  float bv = NEG_INF; int bi = 0x7fffffff;
#pragma unroll
  for (int i = 0; i < 8; ++i) {
    float4 vv = *(const float4*)(dr + i * 256 + lane * 4);
#pragma unroll
    for (int c = 0; c < 4; ++c) {
      float v = (&vv.x)[c];
      rv[i * 4 + c] = v;
      int m = i * 256 + lane * 4 + c;
      if (pair_gt(v, m, bv, bi)) { bv = v; bi = m; }
    }
  }

  // P2: bitonic sort the 64 lane-best pairs, descending
#pragma unroll
  for (int k = 2; k <= 64; k <<= 1) {
#pragma unroll
    for (int j = k >> 1; j >= 1; j >>= 1) {
      float pv = __shfl_xor(bv, j);
      int   pi = __shfl_xor(bi, j);
      bool lower = ((lane & j) == 0);
      bool desc  = ((lane & k) == 0);
      bool pG = pair_gt(pv, pi, bv, bi);
      bool take = (lower == desc) ? pG : !pG;
      bv = take ? pv : bv;
      bi = take ? pi : bi;
    }
  }
  // T0 = 21st largest lane-best. The 21 distinct lane-bests at ranks 0..20
  // are all >= T0, so any element < T0 has >= 21 elements above it =>
  // true top-21 of the row is a subset of {pairs >= T0}.
  const float T0v = __shfl(bv, 20);
  const int   T0i = __shfl(bi, 20);

  // P3: lane-local count + prefix scan + self-indexed compaction (E[M] ~ 25).
  int cntl = 0;
#pragma unroll
  for (int e = 0; e < 32; ++e) {
    float v = rv[e];
    int m = (e >> 2) * 256 + lane * 4 + (e & 3);
    cntl += (!pair_gt(T0v, T0i, v, m)) ? 1 : 0;
  }
  int pre = cntl;
#pragma unroll
  for (int s = 1; s < 64; s <<= 1) {
    int up = __shfl_up(pre, s);
    if (lane >= s) pre += up;
  }
  const int M0 = __shfl(pre, 63);      // total candidates
  int wp = pre - cntl;                 // exclusive prefix = this lane's base
#pragma unroll
  for (int e = 0; e < 32; ++e) {
    float v = rv[e];
    int m = (e >> 2) * 256 + lane * 4 + (e & 3);
    if (!pair_gt(T0v, T0i, v, m)) {
      if (wp < 128) { cvs[wave][wp] = v; cis[wave][wp] = m; }
      ++wp;
    }
  }
  __syncthreads();
  const int M = M0 < 128 ? M0 : 128;

  if (M <= 64) {
    // P4 fast path (common case): single bitonic-64, descending
    float v0 = (lane < M) ? cvs[wave][lane] : NEG_INF;
    int   i0 = (lane < M) ? cis[wave][lane] : 0x7fffffff;
#pragma unroll
    for (int k = 2; k <= 64; k <<= 1) {
#pragma unroll
      for (int j = k >> 1; j >= 1; j >>= 1) {
        float pv = __shfl_xor(v0, j); int pi = __shfl_xor(i0, j);
        bool lower = ((lane & j) == 0);
        bool desc  = ((lane & k) == 0);
        bool pG = pair_gt(pv, pi, v0, i0);
        bool take = (lower == desc) ? pG : !pG;
        v0 = take ? pv : v0; i0 = take ? pi : i0;
      }
    }
    if (lane >= 1 && lane <= K)
      idxout[(size_t)row * K + (lane - 1)] = i0;
  } else {
    // P4 slow path: bitonic-128 over slots (slot = lane + 64*reg), descending
    float v0 = (lane < M)      ? cvs[wave][lane]      : NEG_INF;
    int   i0 = (lane < M)      ? cis[wave][lane]      : 0x7fffffff;
    float v1 = (lane + 64 < M) ? cvs[wave][lane + 64] : NEG_INF;
    int   i1 = (lane + 64 < M) ? cis[wave][lane + 64] : 0x7fffffff;
#pragma unroll
    for (int k = 2; k <= 128; k <<= 1) {
#pragma unroll
      for (int j = k >> 1; j >= 1; j >>= 1) {
        if (j == 64) {
          bool pG = pair_gt(v1, i1, v0, i0);
          float tv = pG ? v1 : v0; int ti = pG ? i1 : i0;
          v1 = pG ? v0 : v1; i1 = pG ? i0 : i1;
          v0 = tv; i0 = ti;
        } else {
          {
            float pv = __shfl_xor(v0, j); int pi = __shfl_xor(i0, j);
            bool lower = ((lane & j) == 0);
            bool desc  = ((lane & k) == 0);
            bool pG = pair_gt(pv, pi, v0, i0);
            bool take = (lower == desc) ? pG : !pG;
            v0 = take ? pv : v0; i0 = take ? pi : i0;
          }
          {
            const int s1 = lane + 64;
            float pv = __shfl_xor(v1, j); int pi = __shfl_xor(i1, j);
            bool lower = ((s1 & j) == 0);
            bool desc  = ((s1 & k) == 0);
            bool pG = pair_gt(pv, pi, v1, i1);
            bool take = (lower == desc) ? pG : !pG;
            v1 = take ? pv : v1; i1 = take ? pi : i1;
          }
        }
      }
    }
    if (lane >= 1 && lane <= K)
      idxout[(size_t)row * K + (lane - 1)] = i0;
  }
}

// ---------------- build [W2 ; W1-W2] from edge weight (O, 2C) ---------------
// fp32 + fp16 hi/lo planes (for the MFMA UV GEMM).
__global__ void wcomb_build(const float* __restrict__ w, float* __restrict__ wc,
                            _Float16* __restrict__ wch, _Float16* __restrict__ wcl,
                            int O, int C) {
  int i = blockIdx.x * 256 + threadIdx.x;
  if (i >= O * C) return;
  int o = i / C, c = i % C;
  float w1 = w[o * 2 * C + c];
  float w2 = w[o * 2 * C + C + c];
  float u = w2;            // u rows
  float v = w1 - w2;       // v rows
  wc[(size_t)o * C + c] = u;
  wc[(size_t)(O + o) * C + c] = v;
  _Float16 uh = (_Float16)u;
  _Float16 vh = (_Float16)v;
  wch[(size_t)o * C + c] = uh;
  wch[(size_t)(O + o) * C + c] = vh;
  wcl[(size_t)o * C + c] = (_Float16)(u - (float)uh);
  wcl[(size_t)(O + o) * C + c] = (_Float16)(v - (float)vh);
}

// ---------------- fp32 C = A(MxK,lda) * B(NcxK)^T (layer-1 UV gemm) ---------
__global__ __launch_bounds__(256) void gemm_abt(
    const float* __restrict__ A, int lda, const float* __restrict__ Bm,
    float* __restrict__ Cm, int ldc, int M, int Nc, int K) {
  __shared__ float As[16][68];
  __shared__ float Bs[16][68];
  const int tid = threadIdx.x;
  const int tx = tid & 15, ty = tid >> 4;
  const int n0 = blockIdx.x * 64;
  const int m0 = blockIdx.y * 64;
  float acc[4][4] = {};
  const int nkt = (K + 15) / 16;
  for (int kt = 0; kt < nkt; ++kt) {
    int k0 = kt * 16;
#pragma unroll
    for (int ph = 0; ph < 4; ++ph) {
      int idx = tid + 256 * ph;
      int k = idx & 15, mr = idx >> 4;
      float v = 0.f;
      if (k0 + k < K) v = A[(size_t)(m0 + mr) * lda + k0 + k];
      As[k][mr] = v;
    }
#pragma unroll
    for (int ph = 0; ph < 4; ++ph) {
      int idx = tid + 256 * ph;
      int k = idx & 15, nr = idx >> 4;
      float v = 0.f;
      if (k0 + k < K) v = Bm[(size_t)(n0 + nr) * K + k0 + k];
      Bs[k][nr] = v;
    }
    __syncthreads();
#pragma unroll
    for (int kk = 0; kk < 16; ++kk) {
      float av[4], bv[4];
#pragma unroll
      for (int r = 0; r < 4; ++r) av[r] = As[kk][4 * ty + r];
#pragma unroll
      for (int c = 0; c < 4; ++c) bv[c] = Bs[kk][4 * tx + c];
#pragma unroll
      for (int r = 0; r < 4; ++r)
#pragma unroll
        for (int c = 0; c < 4; ++c) acc[r][c] = fmaf(av[r], bv[c], acc[r][c]);
    }
    __syncthreads();
  }
#pragma unroll
  for (int r = 0; r < 4; ++r) {
    float4 v = make_float4(acc[r][0], acc[r][1], acc[r][2], acc[r][3]);
    *(float4*)&Cm[(size_t)(m0 + 4 * ty + r) * ldc + n0 + 4 * tx] = v;
  }
}

// ---------------- MFMA bf16 GEMM: C = A(MxK) * B(NcxK)^T, fp32 out ----------
__global__ __launch_bounds__(256) void gemm_mfma_bt(
    const __hip_bfloat16* __restrict__ A, const __hip_bfloat16* __restrict__ Bm,
    float* __restrict__ Cm, int ldc, int M, int Nc, int K) {
  __shared__ __align__(16) __hip_bfloat16 Asm[128][40];
  __shared__ __align__(16) __hip_bfloat16 Bsm[128][40];
  const int tid = threadIdx.x;
  const int lane = tid & 63;
  const int wave = tid >> 6;
  const int wm = (wave >> 1) * 64;
  const int wn = (wave & 1) * 64;
  const int m0 = blockIdx.y * 128;
  const int n0 = blockIdx.x * 128;
  const int srow = tid >> 1, skq = (tid & 1) * 16;
  f32x4 acc[4][4] = {};
#pragma unroll 1
  for (int k0 = 0; k0 < K; k0 += 32) {
    short8 a0 = *(const short8*)&A[(size_t)(m0 + srow) * K + k0 + skq];
    short8 a1 = *(const short8*)&A[(size_t)(m0 + srow) * K + k0 + skq + 8];
    short8 b0 = *(const short8*)&Bm[(size_t)(n0 + srow) * K + k0 + skq];
    short8 b1 = *(const short8*)&Bm[(size_t)(n0 + srow) * K + k0 + skq + 8];
    *(short8*)&Asm[srow][skq] = a0;
    *(short8*)&Asm[srow][skq + 8] = a1;
    *(short8*)&Bsm[srow][skq] = b0;
    *(short8*)&Bsm[srow][skq + 8] = b1;
    __syncthreads();
    short8 af[4], bf_[4];
    const int fr = lane & 15, fq = (lane >> 4) * 8;
#pragma unroll
    for (int s = 0; s < 4; ++s)
      af[s] = *(const short8*)&Asm[wm + s * 16 + fr][fq];
#pragma unroll
    for (int t = 0; t < 4; ++t)
      bf_[t] = *(const short8*)&Bsm[wn + t * 16 + fr][fq];
#pragma unroll
    for (int s = 0; s < 4; ++s)
#pragma unroll
      for (int t = 0; t < 4; ++t)
        acc[s][t] = __builtin_amdgcn_mfma_f32_16x16x32_bf16(af[s], bf_[t], acc[s][t], 0, 0, 0);
    __syncthreads();
  }
  const int ccol = lane & 15, crow = (lane >> 4) * 4;
#pragma unroll
  for (int s = 0; s < 4; ++s)
#pragma unroll
    for (int t = 0; t < 4; ++t)
#pragma unroll
      for (int r = 0; r < 4; ++r) {
        int row = m0 + wm + s * 16 + crow + r;
        int col = n0 + wn + t * 16 + ccol;
        // plain store: H1024 is re-read by seq_part -- keep it L3-resident
        Cm[(size_t)row * ldc + col] = acc[s][t][r];
      }
}

// ---------------- edge conv pass1: h = v_n + u_m; stats + max/min over k ----
// K=20 hardcoded; all 20 indices prefetched then 20 independent gathers.
__global__ void edge_pass1(const float* __restrict__ uv, const int* __restrict__ idx,
                           float* __restrict__ hmax, float* __restrict__ hmin,
                           float* __restrict__ part, int N, int O) {
  int b = blockIdx.y, n = blockIdx.x, o = threadIdx.x;
  size_t row = (size_t)b * N + n;
  const int twoO = 2 * O;
  float vv = uv[row * twoO + O + o];
  const int* ib = idx + row * 20;
  int mi[20];
#pragma unroll
  for (int k = 0; k < 20; ++k) mi[k] = ib[k];
  float hv[20];
#pragma unroll
  for (int k = 0; k < 20; ++k)
    hv[k] = vv + uv[((size_t)b * N + mi[k]) * twoO + o];
  float mx = NEG_INF, mn = POS_INF, s = 0.f, ss = 0.f;
#pragma unroll
  for (int k = 0; k < 20; ++k) {
    mx = fmaxf(mx, hv[k]); mn = fminf(mn, hv[k]);
    s += hv[k]; ss = fmaf(hv[k], hv[k], ss);
  }
  hmax[row * O + o] = mx;
  hmin[row * O + o] = mn;
  __shared__ float2 red[256];
  red[o] = make_float2(s, ss);
  __syncthreads();
  int gsz = O >> 2;
  int lane = o & (gsz - 1);
  for (int off = gsz >> 1; off > 0; off >>= 1) {
    if (lane < off) { red[o].x += red[o + off].x; red[o].y += red[o + off].y; }
    __syncthreads();
  }
  if (lane == 0) {
    int g = o / gsz;
    part[row * 8 + g * 2] = red[o].x;
    part[row * 8 + g * 2 + 1] = red[o].y;
  }
}

__global__ void stats_reduce(const float* __restrict__ part, float* __restrict__ st, int N) {
  int g = blockIdx.x, b = blockIdx.y, tid = threadIdx.x;
  float s = 0.f, ss = 0.f;
  for (int n = tid; n < N; n += 256) {
    size_t base = ((size_t)b * N + n) * 8 + g * 2;
    s += part[base]; ss += part[base + 1];
  }
  __shared__ float2 red[256];
  red[tid] = make_float2(s, ss);
  __syncthreads();
  for (int off = 128; off > 0; off >>= 1) {
    if (tid < off) { red[tid].x += red[tid + off].x; red[tid].y += red[tid + off].y; }
    __syncthreads();
  }
  if (tid == 0) { st[(b * 4 + g) * 2] = red[0].x; st[(b * 4 + g) * 2 + 1] = red[0].y; }
}

__global__ void edge_pass2(const float* __restrict__ hmax, const float* __restrict__ hmin,
                           const float* __restrict__ st,
                           const float* __restrict__ gw, const float* __restrict__ gb,
                           float* __restrict__ outbase, __hip_bfloat16* __restrict__ outbf,
                           _Float16* __restrict__ outh, _Float16* __restrict__ outl,
                           int N, int O, int K, int coloff, int total) {
  int i = blockIdx.x * 256 + threadIdx.x;
  if (i >= total) return;
  int o = i % O;
  int n = (i / O) % N;
  int b = i / (O * N);
  int gsz = O >> 2;
  int g = o / gsz;
  float S = st[(b * 4 + g) * 2], SS = st[(b * 4 + g) * 2 + 1];
  float cnt = (float)N * (float)K * (float)gsz;
  float mean = S / cnt;
  float var = SS / cnt - mean * mean;
  float rs = rsqrtf(var + 1e-5f);
  float wf = gw[o], bf = gb[o];
  float Mv = (wf >= 0.f) ? hmax[i] : hmin[i];
  float val = lk((Mv - mean) * rs * wf + bf);
  size_t pos = ((size_t)b * N + n) * 512 + coloff + o;
  outbase[pos] = val;
  outbf[pos] = __float2bfloat16(val);
  if (outh) {
    // hi/lo fp16 planes, row stride 256 (cols 0-255 of HCAT only)
    size_t posh = ((size_t)b * N + n) * 256 + coloff + o;
    _Float16 h = (_Float16)val;
    outh[posh] = h;
    outl[posh] = (_Float16)(val - (float)h);
  }
}

// ---------------- gn_seq stats: grid (8,128); one f32x4-col x 16 rows -------
__global__ __launch_bounds__(256) void seq_part(const float* __restrict__ h,
                                                float4* __restrict__ pq, int N) {
  const int b = blockIdx.x, chunk = blockIdx.y;
  const int tid = threadIdx.x;        // cols 4*tid .. 4*tid+3
  const int nbeg = chunk * 16;
  float mx0 = NEG_INF, mx1 = NEG_INF, mx2 = NEG_INF, mx3 = NEG_INF;
  float mn0 = POS_INF, mn1 = POS_INF, mn2 = POS_INF, mn3 = POS_INF;
  float s0 = 0.f, s1 = 0.f, s2 = 0.f, s3 = 0.f;
  float q0 = 0.f, q1 = 0.f, q2 = 0.f, q3 = 0.f;
#pragma unroll
  for (int n = 0; n < 16; ++n) {
    f32x4 v = *(const f32x4*)&h[((size_t)b * N + nbeg + n) * 1024 + 4 * tid];
    mx0 = fmaxf(mx0, v[0]); mn0 = fminf(mn0, v[0]); s0 += v[0]; q0 = fmaf(v[0], v[0], q0);
    mx1 = fmaxf(mx1, v[1]); mn1 = fminf(mn1, v[1]); s1 += v[1]; q1 = fmaf(v[1], v[1], q1);
    mx2 = fmaxf(mx2, v[2]); mn2 = fminf(mn2, v[2]); s2 += v[2]; q2 = fmaf(v[2], v[2], q2);
    mx3 = fmaxf(mx3, v[3]); mn3 = fminf(mn3, v[3]); s3 += v[3]; q3 = fmaf(v[3], v[3], q3);
  }
  const size_t base = ((size_t)(b * 128 + chunk)) * 1024 + 4 * tid;
  pq[base + 0] = make_float4(mx0, mn0, s0, q0);
  pq[base + 1] = make_float4(mx1, mn1, s1, q1);
  pq[base + 2] = make_float4(mx2, mn2, s2, q2);
  pq[base + 3] = make_float4(mx3, mn3, s3, q3);
}

__global__ void seq_fin(const float4* __restrict__ pq, float* __restrict__ st16,
                        float* __restrict__ maxv, float* __restrict__ minv) {
  int b = blockIdx.y;
  int tid = threadIdx.x;
  int c = blockIdx.x * 256 + tid;
  float mx = NEG_INF, mn = POS_INF, s = 0.f, ss = 0.f;
#pragma unroll 8
  for (int ch = 0; ch < 128; ++ch) {
    float4 p = pq[((size_t)(b * 128 + ch)) * 1024 + c];
    mx = fmaxf(mx, p.x); mn = fminf(mn, p.y);
    s += p.z; ss += p.w;
  }
  maxv[b * 1024 + c] = mx;
  minv[b * 1024 + c] = mn;
  __shared__ float2 red[256];
  red[tid] = make_float2(s, ss);
  __syncthreads();
  int lane = tid & 63;
  for (int off = 32; off > 0; off >>= 1) {
    if (lane < off) { red[tid].x += red[tid + off].x; red[tid].y += red[tid + off].y; }
    __syncthreads();
  }
  if (lane == 0) {
    int g = c >> 6;
    st16[(b * 16 + g) * 2] = red[tid].x;
    st16[(b * 16 + g) * 2 + 1] = red[tid].y;
  }
}

__global__ void seq_apply(const float* __restrict__ st16, const float* __restrict__ maxv,
                          const float* __restrict__ minv, const float* __restrict__ gw,
                          const float* __restrict__ gb, float* __restrict__ g, int N) {
  int i = blockIdx.x * 256 + threadIdx.x;
  if (i >= 8 * 1024) return;
  int b = i >> 10, c = i & 1023;
  int grp = c >> 6;
  float S = st16[(b * 16 + grp) * 2], SS = st16[(b * 16 + grp) * 2 + 1];
  float cnt = (float)N * 64.f;
  float mean = S / cnt;
  float var = SS / cnt - mean * mean;
  float rs = rsqrtf(var + 1e-5f);
  float wf = gw[c], bf = gb[c];
  float Mv = (wf >= 0.f) ? maxv[i] : minv[i];
  g[i] = lk((Mv - mean) * rs * wf + bf);
}

// ---------------- MLP head, stage 1: fc1 (1024->512), one wave per output ---
__global__ __launch_bounds__(256) void fc1_par(
    const float* __restrict__ gvec, const float* __restrict__ w,
    const float* __restrict__ bias, float* __restrict__ z1) {
  __shared__ float xin[1024];
  const int b = blockIdx.y, tid = threadIdx.x;
  const int lane = tid & 63, wave = tid >> 6;
  for (int i = tid; i < 1024; i += 256) xin[i] = gvec[b * 1024 + i];
  __syncthreads();
  const int obase = blockIdx.x * 16 + wave * 4;
#pragma unroll
  for (int i = 0; i < 4; ++i) {
    const int o = obase + i;
    const float* wr = w + (size_t)o * 1024;
    float acc = 0.f;
#pragma unroll
    for (int r = 0; r < 4; ++r) {
      float4 wv = *(const float4*)(wr + r * 256 + lane * 4);
      float4 xv = *(const float4*)(&xin[r * 256 + lane * 4]);
      acc = fmaf(wv.x, xv.x, acc);
      acc = fmaf(wv.y, xv.y, acc);
      acc = fmaf(wv.z, xv.z, acc);
      acc = fmaf(wv.w, xv.w, acc);
    }
#pragma unroll
    for (int s = 1; s < 64; s <<= 1) acc += __shfl_xor(acc, s);
    if (lane == 0) z1[b * 512 + o] = acc + bias[o];
  }
}

// ---------------- MLP head, stage 2: ln1 -> fc2 -> ln2 -> fc3 -> ln3 -> fc4 -
__global__ __launch_bounds__(512) void mlp_tail(
    const float* __restrict__ z1in,
    const float* __restrict__ ln1w, const float* __restrict__ ln1b,
    const float* __restrict__ fc2w, const float* __restrict__ fc2b,
    const float* __restrict__ ln2w, const float* __restrict__ ln2b,
    const float* __restrict__ fc3w, const float* __restrict__ fc3b,
    const float* __restrict__ ln3w, const float* __restrict__ ln3b,
    const float* __restrict__ fc4w, const float* __restrict__ fc4b,
    void* __restrict__ out, const int* __restrict__ flag) {
  __shared__ float s1[512];
  __shared__ float z2[256];
  __shared__ float s2[256];
  __shared__ float z3[64];
  __shared__ float s3[64];
  __shared__ float2 red[8];
  const int b = blockIdx.x, tid = threadIdx.x;
  const int lane = tid & 63, wave = tid >> 6;

  // ---- ln1 over z1 (512) + leaky ----
  float v1 = z1in[b * 512 + tid];
  {
    float s = v1, ss = v1 * v1;
#pragma unroll
    for (int o = 1; o < 64; o <<= 1) { s += __shfl_xor(s, o); ss += __shfl_xor(ss, o); }
    if (lane == 0) red[wave] = make_float2(s, ss);
  }
  __syncthreads();
  {
    float S = 0.f, SS = 0.f;
#pragma unroll
    for (int i = 0; i < 8; ++i) { S += red[i].x; SS += red[i].y; }
    float mean = S / 512.f;
    float var = SS / 512.f - mean * mean;
    float rs = rsqrtf(var + 1e-5f);
    s1[tid] = lk((v1 - mean) * rs * ln1w[tid] + ln1b[tid]);
  }
  __syncthreads();

  // ---- fc2: 256 outputs x 512 in; 8 waves -> 32 outputs/wave ----
#pragma unroll 1
  for (int i = 0; i < 32; ++i) {
    const int o = wave * 32 + i;
    const float* wr = fc2w + (size_t)o * 512;
    float acc = 0.f;
#pragma unroll
    for (int r = 0; r < 2; ++r) {
      float4 wv = *(const float4*)(wr + r * 256 + lane * 4);
      float4 xv = *(const float4*)(&s1[r * 256 + lane * 4]);
      acc = fmaf(wv.x, xv.x, acc);
      acc = fmaf(wv.y, xv.y, acc);
      acc = fmaf(wv.z, xv.z, acc);
      acc = fmaf(wv.w, xv.w, acc);
    }
#pragma unroll
    for (int s = 1; s < 64; s <<= 1) acc += __shfl_xor(acc, s);
    if (lane == 0) z2[o] = acc + fc2b[o];
  }
  __syncthreads();

  // ---- ln2 over 256 + leaky ----
  float v2 = (tid < 256) ? z2[tid] : 0.f;
  {
    float s = v2, ss = v2 * v2;
#pragma unroll
    for (int o = 1; o < 64; o <<= 1) { s += __shfl_xor(s, o); ss += __shfl_xor(ss, o); }
    if (lane == 0) red[wave] = make_float2(s, ss);
  }
  __syncthreads();
  {
    float S = 0.f, SS = 0.f;
#pragma unroll
    for (int i = 0; i < 4; ++i) { S += red[i].x; SS += red[i].y; }
    float mean = S / 256.f;
    float var = SS / 256.f - mean * mean;
    float rs = rsqrtf(var + 1e-5f);
    if (tid < 256) s2[tid] = lk((v2 - mean) * rs * ln2w[tid] + ln2b[tid]);
  }
  __syncthreads();

  // ---- fc3: 64 outputs x 256 in; 8 waves -> 8 outputs/wave ----
#pragma unroll 1
  for (int i = 0; i < 8; ++i) {
    const int o = wave * 8 + i;
    const float* wr = fc3w + (size_t)o * 256;
    float4 wv = *(const float4*)(wr + lane * 4);
    float4 xv = *(const float4*)(&s2[lane * 4]);
    float acc = fmaf(wv.x, xv.x, 0.f);
    acc = fmaf(wv.y, xv.y, acc);
    acc = fmaf(wv.z, xv.z, acc);
    acc = fmaf(wv.w, xv.w, acc);
#pragma unroll
    for (int s = 1; s < 64; s <<= 1) acc += __shfl_xor(acc, s);
    if (lane == 0) z3[o] = acc + fc3b[o];
  }
  __syncthreads();

  // ---- ln3 over 64 + leaky (wave 0 only) ----
  if (wave == 0) {
    float v3 = z3[lane];
    float s = v3, ss = v3 * v3;
#pragma unroll
    for (int o = 1; o < 64; o <<= 1) { s += __shfl_xor(s, o); ss += __shfl_xor(ss, o); }
    float mean = s / 64.f;
    float var = ss / 64.f - mean * mean;
    float rs = rsqrtf(var + 1e-5f);
    s3[lane] = lk((v3 - mean) * rs * ln3w[lane] + ln3b[lane]);
  }
  __syncthreads();

  // ---- fc4: 2 outputs x 64 (waves 0,1) ----
  if (wave < 2) {
    float acc = s3[lane] * fc4w[wave * 64 + lane];
#pragma unroll
    for (int s = 1; s < 64; s <<= 1) acc += __shfl_xor(acc, s);
    if (lane == 0) {
      acc += fc4b[wave];
      if (*flag) ((__hip_bfloat16*)out)[b * 2 + wave] = __float2bfloat16(acc);
      else       ((float*)out)[b * 2 + wave] = acc;
    }
  }
}

// ---------------- host-side dispatch helpers -----------------------
static void launch_sq(int C, const float* xin, int ldx, float* sqb, int BN, hipStream_t s) {
  dim3 g((BN + 255) / 256);
  if (C == 3)       sq_kernel<3><<<g, 256, 0, s>>>(xin, ldx, sqb, BN);
  else if (C == 64) sq_kernel<64><<<g, 256, 0, s>>>(xin, ldx, sqb, BN);
  else              sq_kernel<128><<<g, 256, 0, s>>>(xin, ldx, sqb, BN);
}

extern "C" void kernel_launch(void* const* d_in, const int* in_sizes, int n_in,
                              void* d_out, int out_size, void* d_ws, size_t ws_size,
                              hipStream_t stream) {
  (void)out_size; (void)ws_size;
  const int B = 8, N = 2048, KNN = 20;
  const int BN = B * N;

  float* base = (float*)d_ws;
  size_t off = 0;
  auto alloc = [&](size_t nf) { float* p = base + off; off += nf; return p; };

  int*   FLAG  = (int*)alloc(16);
  float* XF    = alloc((size_t)BN * 3);
  float* HCAT  = alloc((size_t)BN * 512);
  float* DISTB = alloc((size_t)BN * 2048);   // DIST during knn; then UV|HMAX|HMIN|H1024
  float* UV    = DISTB;                       // BN*512
  float* HMAX  = DISTB + (size_t)BN * 512;    // BN*256
  float* HMIN  = DISTB + (size_t)BN * 768;    // BN*256
  float* H1024 = DISTB + (size_t)BN * 1024;   // BN*1024
  float* SQB   = alloc(BN);
  float* WCOMB = alloc((size_t)512 * 128);
  float* PART  = alloc((size_t)BN * 8);
  float* ST4   = alloc(64);
  float* ST16  = alloc(512);
  float* PQST  = alloc((size_t)8 * 128 * 1024 * 4);
  float* MAXV  = alloc(8 * 1024);
  float* MINV  = alloc(8 * 1024);
  float* GVEC  = alloc(8 * 1024);
  float* Z1    = alloc(8 * 512);
  int*   IDX = (int*)alloc((size_t)BN * KNN);
  __hip_bfloat16* HCATBF = (__hip_bfloat16*)alloc((size_t)BN * 256);  // BN*512 bf16
  __hip_bfloat16* WMBF   = (__hip_bfloat16*)alloc(262144);            // 1024*512 bf16
  _Float16* HH  = (_Float16*)alloc((size_t)BN * 128);  // BN*256 fp16 hi (stride 256)
  _Float16* HL  = (_Float16*)alloc((size_t)BN * 128);  // BN*256 fp16 lo (stride 256)
  _Float16* WCH = (_Float16*)alloc((size_t)512 * 64);  // 512*128 fp16 hi
  _Float16* WCL = (_Float16*)alloc((size_t)512 * 64);  // 512*128 fp16 lo

  // converted fp32 weights
  ConvTable ct;
  float* conv_dst[30];
  for (int i = 0; i < 30; ++i) {
    int n = in_sizes[i];
    conv_dst[i] = alloc((size_t)((n + 15) & ~15));
    ct.src[i] = d_in[i];
    ct.dst[i] = conv_dst[i];
    ct.n[i] = n;
  }
  ct.dst[0] = XF; ct.n[0] = BN * 3;

  const float* W_[4]  = {conv_dst[1], conv_dst[4], conv_dst[7], conv_dst[10]};
  const float* GW_[4] = {conv_dst[2], conv_dst[5], conv_dst[8], conv_dst[11]};
  const float* GB_[4] = {conv_dst[3], conv_dst[6], conv_dst[9], conv_dst[12]};
  const float* WM = conv_dst[13];
  const float* GMW = conv_dst[14], *GMB = conv_dst[15];
  const float* FC1W = conv_dst[16], *FC1B = conv_dst[17], *LN1W = conv_dst[18], *LN1B = conv_dst[19];
  const float* FC2W = conv_dst[20], *FC2B = conv_dst[21], *LN2W = conv_dst[22], *LN2B = conv_dst[23];
  const float* FC3W = conv_dst[24], *FC3B = conv_dst[25], *LN3W = conv_dst[26], *LN3B = conv_dst[27];
  const float* FC4W = conv_dst[28], *FC4B = conv_dst[29];

  detect_dtype<<<dim3(1), 64, 0, stream>>>((const unsigned short*)d_in[0], FLAG);
  conv_all<<<dim3(256, 30), 256, 0, stream>>>(ct, FLAG);
  convf2b<<<dim3(2048), 256, 0, stream>>>(WM, WMBF, 1024 * 512);

  const int Cs[4]     = {3, 64, 64, 128};
  const int Os[4]     = {64, 64, 128, 256};
  const int incol[4]  = {0, 0, 64, 128};
  const int outcol[4] = {0, 64, 128, 256};

  for (int l = 0; l < 4; ++l) {
    const int C = Cs[l], O = Os[l], twoO = 2 * O;
    const float* xin = (l == 0) ? XF : (HCAT + incol[l]);
    const int ldx = (l == 0) ? 3 : 512;

    launch_sq(C, xin, ldx, SQB, BN, stream);
    if (l == 0)
      dist_gemm<<<dim3(N / 64, N / 64, B), 256, 0, stream>>>(xin, ldx, SQB, DISTB, N, C);
    else
      dist_mfma<<<dim3(N / 128, N / 128, B), 256, 0, stream>>>(HH + incol[l], HL + incol[l],
                                                               SQB, DISTB, N, C);
    knn_select<<<dim3(BN / 4), 256, 0, stream>>>(DISTB, IDX, KNN);
    wcomb_build<<<dim3((O * C + 255) / 256), 256, 0, stream>>>(W_[l], WCOMB, WCH, WCL, O, C);
    if (l == 0)
      gemm_abt<<<dim3(twoO / 64, BN / 64), 256, 0, stream>>>(xin, ldx, WCOMB, UV, twoO, BN, twoO, C);
    else
      gemm_hl<<<dim3(twoO / 128, BN / 128), 256, 0, stream>>>(HH + incol[l], HL + incol[l],
                                                              WCH, WCL, UV, twoO, C);
    edge_pass1<<<dim3(N, B), O, 0, stream>>>(UV, IDX, HMAX, HMIN, PART, N, O);
    stats_reduce<<<dim3(4, B), 256, 0, stream>>>(PART, ST4, N);
    int tot = BN * O;
    // layer 4's output (cols 256-511) never feeds a distance GEMM: skip hi/lo
    _Float16* oh = (l == 3) ? nullptr : HH;
    _Float16* ol = (l == 3) ? nullptr : HL;
    edge_pass2<<<dim3((tot + 255) / 256), 256, 0, stream>>>(HMAX, HMIN, ST4, GW_[l], GB_[l],
                                                            HCAT, HCATBF, oh, ol,
                                                            N, O, KNN, outcol[l], tot);
  }

  gemm_mfma_bt<<<dim3(1024 / 128, BN / 128), 256, 0, stream>>>(HCATBF, WMBF, H1024, 1024, BN, 1024, 512);
  seq_part<<<dim3(8, 128), 256, 0, stream>>>(H1024, (float4*)PQST, N);
  seq_fin<<<dim3(4, 8), 256, 0, stream>>>((const float4*)PQST, ST16, MAXV, MINV);
  seq_apply<<<dim3(32), 256, 0, stream>>>(ST16, MAXV, MINV, GMW, GMB, GVEC, N);

  fc1_par<<<dim3(32, 8), 256, 0, stream>>>(GVEC, FC1W, FC1B, Z1);
  mlp_tail<<<dim3(8), 512, 0, stream>>>(Z1, LN1W, LN1B,
                                        FC2W, FC2B, LN2W, LN2B,
                                        FC3W, FC3B, LN3W, LN3B,
                                        FC4W, FC4B, d_out, FLAG);
}